// Round 1
// baseline (693.798 us; speedup 1.0000x reference)
//
#include <hip/hip_runtime.h>
#include <math.h>

#define DIM 256
#define HEADS 8
#define HD 32

// ---------------- avg pool (from 256x64x64) ----------------
__global__ __launch_bounds__(256) void avgpool_kernel(const float* __restrict__ x,
                                                      float* __restrict__ out, int lgS) {
  int s = 1 << lgS;
  int lgHs = 6 - lgS;
  int Hs = 1 << lgHs;
  int id = blockIdx.x * 256 + threadIdx.x;           // c * Ns + n
  int c = id >> (2 * lgHs);
  int n = id & ((1 << (2 * lgHs)) - 1);
  int y = (n >> lgHs) << lgS;
  int x0 = (n & (Hs - 1)) << lgS;
  const float* base = x + c * 4096 + y * 64 + x0;
  float sum = 0.f;
  for (int dy = 0; dy < s; ++dy)
    for (int dx = 0; dx < s; ++dx)
      sum += base[dy * 64 + dx];
  out[id] = sum / (float)(s * s);
}

// ---------------- fused depthwise 3x3 (dw + pos), SAME zero pad ----------------
__global__ __launch_bounds__(256) void dwconv_kernel(const float* __restrict__ xs,
    const float* __restrict__ dw_w, const float* __restrict__ dw_b,
    const float* __restrict__ pos_w, const float* __restrict__ pos_b,
    float* __restrict__ xdw, float* __restrict__ pos, int lgHs) {
  int Hs = 1 << lgHs;
  int Ns = Hs * Hs;
  int id = blockIdx.x * 256 + threadIdx.x;           // c * Ns + n
  int c = id >> (2 * lgHs);
  int n = id & (Ns - 1);
  int y = n >> lgHs, x = n & (Hs - 1);
  const float* w1 = dw_w + c * 9;
  const float* w2 = pos_w + c * 9;
  const float* src = xs + c * Ns;
  float s1 = dw_b[c], s2 = pos_b[c];
  #pragma unroll
  for (int ky = 0; ky < 3; ++ky) {
    int yy = y + ky - 1;
    bool yok = (yy >= 0) && (yy < Hs);
    #pragma unroll
    for (int kx = 0; kx < 3; ++kx) {
      int xx = x + kx - 1;
      bool ok = yok && (xx >= 0) && (xx < Hs);
      float v = ok ? src[yy * Hs + xx] : 0.f;
      s1 += v * w1[ky * 3 + kx];
      s2 += v * w2[ky * 3 + kx];
    }
  }
  xdw[id] = s1;
  pos[id] = s2;
}

// ---------------- fp32 tiled GEMM: C[M,N] = A[M,K]*B[K,N] + bias (+pos for q,k) ----
// A row-major, B row-major. 64x64 tile, 256 threads, 4x4 micro-tile, K-step 16.
// M,N multiples of 64; K multiple of 16 (true for all uses here).
__global__ __launch_bounds__(256) void gemm_kernel(const float* __restrict__ A,
    const float* __restrict__ B, float* __restrict__ C,
    const float* __restrict__ bias, const float* __restrict__ pos,
    int M, int N, int K) {
  __shared__ __align__(16) float a_lds[16][64];
  __shared__ __align__(16) float b_lds[16][64];
  const int t = threadIdx.x;
  const int cb = blockIdx.x * 64;
  const int rb = blockIdx.y * 64;
  const int tr = (t >> 4) << 2, tc = (t & 15) << 2;
  const int ar = t >> 2, ak = (t & 3) << 2;
  const int bi = t << 2;
  const int bk = bi >> 6, bc = bi & 63;
  float acc[4][4] = {};
  for (int k0 = 0; k0 < K; k0 += 16) {
    float4 av4 = *(const float4*)(A + (rb + ar) * K + k0 + ak);
    float4 bv4 = *(const float4*)(B + (size_t)(k0 + bk) * N + cb + bc);
    __syncthreads();
    a_lds[ak + 0][ar] = av4.x;
    a_lds[ak + 1][ar] = av4.y;
    a_lds[ak + 2][ar] = av4.z;
    a_lds[ak + 3][ar] = av4.w;
    *(float4*)&b_lds[bk][bc] = bv4;
    __syncthreads();
    #pragma unroll
    for (int kk = 0; kk < 16; ++kk) {
      float4 a = *(const float4*)&a_lds[kk][tr];
      float4 b = *(const float4*)&b_lds[kk][tc];
      acc[0][0] += a.x * b.x; acc[0][1] += a.x * b.y; acc[0][2] += a.x * b.z; acc[0][3] += a.x * b.w;
      acc[1][0] += a.y * b.x; acc[1][1] += a.y * b.y; acc[1][2] += a.y * b.z; acc[1][3] += a.y * b.w;
      acc[2][0] += a.z * b.x; acc[2][1] += a.z * b.y; acc[2][2] += a.z * b.z; acc[2][3] += a.z * b.w;
      acc[3][0] += a.w * b.x; acc[3][1] += a.w * b.y; acc[3][2] += a.w * b.z; acc[3][3] += a.w * b.w;
    }
  }
  #pragma unroll
  for (int i = 0; i < 4; ++i) {
    int o = rb + tr + i;
    float bs = bias[o];
    float4 v;
    v.x = acc[i][0] + bs; v.y = acc[i][1] + bs; v.z = acc[i][2] + bs; v.w = acc[i][3] + bs;
    if (pos != nullptr && o < 2 * DIM) {
      const float* pr = pos + (size_t)(o & (DIM - 1)) * N + cb + tc;
      v.x += pr[0]; v.y += pr[1]; v.z += pr[2]; v.w += pr[3];
    }
    *(float4*)(C + (size_t)o * N + cb + tc) = v;
  }
}

// ---------------- attention: flash-style, 64-query tile per block ----------------
// qkv layout: [768][Ns]; q = rows 0..255 (head h -> rows h*32..h*32+31), k = +256, v = +512
// out[c][n] with c = h*32+d. Unnormalized softmax (logits are O(1) for this data).
__global__ __launch_bounds__(256) void attn_kernel(const float* __restrict__ qkv,
                                                   float* __restrict__ out, int Ns) {
  __shared__ __align__(16) float q_lds[32 * 64];
  __shared__ __align__(16) float k_lds[32 * 64];
  __shared__ __align__(16) float vt_lds[64 * 36];   // transposed [m][d], pad 36
  __shared__ __align__(16) float p_lds[64 * 65];    // exp'd scores [n][m], pad 65
  const int t = threadIdx.x;
  const int h = blockIdx.y;
  const int n0 = blockIdx.x * 64;
  const float* qg = qkv + (size_t)(h * HD) * Ns;
  const float* kg = qkv + (size_t)(DIM + h * HD) * Ns;
  const float* vg = qkv + (size_t)(2 * DIM + h * HD) * Ns;
  #pragma unroll
  for (int i = 0; i < 8; ++i) {
    int idx = t + i * 256;
    int d = idx >> 6, nn = idx & 63;
    q_lds[d * 64 + nn] = qg[(size_t)d * Ns + n0 + nn] * 0.17677669529663689f; // 1/sqrt(32)
  }
  const int nq = t & 63;       // query row owned in phases 1 & 3
  const int dg = t >> 6;       // wave id: d-group in phase 3, m-group in phase 1
  float acc[8] = {0.f, 0.f, 0.f, 0.f, 0.f, 0.f, 0.f, 0.f};
  float lsum = 0.f;
  for (int m0 = 0; m0 < Ns; m0 += 64) {
    __syncthreads();   // protect k/v LDS from previous chunk's phase-3 readers
    #pragma unroll
    for (int i = 0; i < 8; ++i) {
      int idx = t + i * 256;
      int d = idx >> 6, nn = idx & 63;
      k_lds[d * 64 + nn] = kg[(size_t)d * Ns + m0 + nn];
      vt_lds[nn * 36 + d] = vg[(size_t)d * Ns + m0 + nn];
    }
    __syncthreads();
    // phase 1: S[nq][mg*16 .. +15] = Q^T K, exp'd into p_lds
    {
      float s[16];
      #pragma unroll
      for (int i = 0; i < 16; ++i) s[i] = 0.f;
      const int mg = dg * 16;
      #pragma unroll
      for (int d = 0; d < 32; ++d) {
        float qv = q_lds[d * 64 + nq];
        const float* kr = &k_lds[d * 64 + mg];
        float4 k0 = *(const float4*)(kr);
        float4 k1 = *(const float4*)(kr + 4);
        float4 k2 = *(const float4*)(kr + 8);
        float4 k3 = *(const float4*)(kr + 12);
        s[0]  += qv * k0.x; s[1]  += qv * k0.y; s[2]  += qv * k0.z; s[3]  += qv * k0.w;
        s[4]  += qv * k1.x; s[5]  += qv * k1.y; s[6]  += qv * k1.z; s[7]  += qv * k1.w;
        s[8]  += qv * k2.x; s[9]  += qv * k2.y; s[10] += qv * k2.z; s[11] += qv * k2.w;
        s[12] += qv * k3.x; s[13] += qv * k3.y; s[14] += qv * k3.z; s[15] += qv * k3.w;
      }
      float* pr = &p_lds[nq * 65 + mg];
      #pragma unroll
      for (int i = 0; i < 16; ++i) pr[i] = __expf(s[i]);
    }
    __syncthreads();
    // phase 3: out[d][nq] accumulation; each thread owns (nq, d = dg*8 .. dg*8+7)
    {
      const float* pr = &p_lds[nq * 65];
      const float* vb = &vt_lds[dg * 8];
      #pragma unroll 8
      for (int m = 0; m < 64; ++m) {
        float p = pr[m];
        lsum += p;                      // same value across the 4 d-groups of row nq
        float4 va = *(const float4*)(vb + m * 36);
        float4 vc = *(const float4*)(vb + m * 36 + 4);
        acc[0] += p * va.x; acc[1] += p * va.y; acc[2] += p * va.z; acc[3] += p * va.w;
        acc[4] += p * vc.x; acc[5] += p * vc.y; acc[6] += p * vc.z; acc[7] += p * vc.w;
      }
    }
  }
  float inv = 1.0f / lsum;
  #pragma unroll
  for (int j = 0; j < 8; ++j) {
    int c = h * HD + dg * 8 + j;
    out[(size_t)c * Ns + n0 + nq] = acc[j] * inv;
  }
}

// ---------------- bilinear upsample to 64x64 (jax half-pixel + edge clamp) -------
__global__ __launch_bounds__(256) void upsample_kernel(const float* __restrict__ src,
                                                       float* __restrict__ dst, int lgHs) {
  int Hs = 1 << lgHs;
  int id = blockIdx.x * 256 + threadIdx.x;           // c*4096 + y*64 + x
  int c = id >> 12, n = id & 4095;
  int y = n >> 6, x = n & 63;
  float sc = (float)Hs / 64.0f;
  float fy = ((float)y + 0.5f) * sc - 0.5f;
  float fx = ((float)x + 0.5f) * sc - 0.5f;
  float fy0 = floorf(fy), fx0 = floorf(fx);
  int y0 = (int)fy0, x0 = (int)fx0;
  float ty = fy - fy0, tx = fx - fx0;
  int y0c = min(max(y0, 0), Hs - 1), y1c = min(max(y0 + 1, 0), Hs - 1);
  int x0c = min(max(x0, 0), Hs - 1), x1c = min(max(x0 + 1, 0), Hs - 1);
  const float* s = src + c * Hs * Hs;
  float v00 = s[y0c * Hs + x0c], v01 = s[y0c * Hs + x1c];
  float v10 = s[y1c * Hs + x0c], v11 = s[y1c * Hs + x1c];
  float v0 = v00 + (v01 - v00) * tx;
  float v1 = v10 + (v11 - v10) * tx;
  dst[id] = v0 + (v1 - v0) * ty;
}

extern "C" void kernel_launch(void* const* d_in, const int* in_sizes, int n_in,
                              void* d_out, int out_size, void* d_ws, size_t ws_size,
                              hipStream_t stream) {
  const float* x     = (const float*)d_in[0];
  const float* dw_w  = (const float*)d_in[1];
  const float* dw_b  = (const float*)d_in[2];
  const float* pw_w  = (const float*)d_in[3];
  const float* pw_b  = (const float*)d_in[4];
  const float* pos_w = (const float*)d_in[5];
  const float* pos_b = (const float*)d_in[6];
  const float* fus_w = (const float*)d_in[7];
  const float* fus_b = (const float*)d_in[8];
  float* out = (float*)d_out;
  float* ws = (float*)d_ws;

  // workspace layout (floats): total 9,043,968 (~36.2 MB)
  float* xs2  = ws;                  // 256*32*32
  float* xs4  = xs2 + 262144;        // 256*16*16
  float* xdw  = xs4 + 65536;         // 256*4096 (reused per scale)
  float* posb = xdw + 1048576;       // 256*4096 (reused per scale)
  float* qkv  = posb + 1048576;      // 768*4096 (reused per scale)
  float* cat  = qkv + 3145728;       // 768*4096
  float* out2 = cat + 3145728;       // 256*1024
  float* out4 = out2 + 262144;       // 256*256

  avgpool_kernel<<<1024, 256, 0, stream>>>(x, xs2, 1);
  avgpool_kernel<<<256, 256, 0, stream>>>(x, xs4, 2);

  // ---- scale 1 (Hs=64, Ns=4096); attention writes cat rows 0..255 ----
  dwconv_kernel<<<4096, 256, 0, stream>>>(x, dw_w, dw_b, pos_w, pos_b, xdw, posb, 6);
  gemm_kernel<<<dim3(64, 12), 256, 0, stream>>>(pw_w, xdw, qkv, pw_b, posb, 768, 4096, 256);
  attn_kernel<<<dim3(64, 8), 256, 0, stream>>>(qkv, cat, 4096);

  // ---- scale 2 (Hs=32, Ns=1024) ----
  dwconv_kernel<<<1024, 256, 0, stream>>>(xs2, dw_w + 2304, dw_b + 256, pos_w + 2304,
                                          pos_b + 256, xdw, posb, 5);
  gemm_kernel<<<dim3(16, 12), 256, 0, stream>>>(pw_w + 196608, xdw, qkv, pw_b + 768,
                                                posb, 768, 1024, 256);
  attn_kernel<<<dim3(16, 8), 256, 0, stream>>>(qkv, out2, 1024);

  // ---- scale 4 (Hs=16, Ns=256) ----
  dwconv_kernel<<<256, 256, 0, stream>>>(xs4, dw_w + 4608, dw_b + 512, pos_w + 4608,
                                         pos_b + 512, xdw, posb, 4);
  gemm_kernel<<<dim3(4, 12), 256, 0, stream>>>(pw_w + 393216, xdw, qkv, pw_b + 1536,
                                               posb, 768, 256, 256);
  attn_kernel<<<dim3(4, 8), 256, 0, stream>>>(qkv, out4, 256);

  // ---- upsample into cat rows 256..511 and 512..767 ----
  upsample_kernel<<<4096, 256, 0, stream>>>(out2, cat + 256 * 4096, 5);
  upsample_kernel<<<4096, 256, 0, stream>>>(out4, cat + 512 * 4096, 4);

  // ---- fusion GEMM: out[256][4096] = fusion_w[256][768] * cat[768][4096] + b ----
  gemm_kernel<<<dim3(64, 4), 256, 0, stream>>>(fus_w, cat, out, fus_b, nullptr,
                                               256, 4096, 768);
}

// Round 2
// 397.424 us; speedup vs baseline: 1.7457x; 1.7457x over previous
//
#include <hip/hip_runtime.h>
#include <math.h>

#define DIM 256
#define HEADS 8
#define HD 32

typedef __attribute__((ext_vector_type(8))) short bf16x8;
typedef __attribute__((ext_vector_type(4))) float f32x4;

__device__ __forceinline__ unsigned short f2bf(float f) {
  unsigned int u = __float_as_uint(f);
  unsigned int r = u + 0x7fff + ((u >> 16) & 1);   // round-to-nearest-even
  return (unsigned short)(r >> 16);
}

// ---------------- avg pool (from 256x64x64) ----------------
__global__ __launch_bounds__(256) void avgpool_kernel(const float* __restrict__ x,
                                                      float* __restrict__ out, int lgS) {
  int s = 1 << lgS;
  int lgHs = 6 - lgS;
  int Hs = 1 << lgHs;
  int id = blockIdx.x * 256 + threadIdx.x;           // c * Ns + n
  int c = id >> (2 * lgHs);
  int n = id & ((1 << (2 * lgHs)) - 1);
  int y = (n >> lgHs) << lgS;
  int x0 = (n & (Hs - 1)) << lgS;
  const float* base = x + c * 4096 + y * 64 + x0;
  float sum = 0.f;
  for (int dy = 0; dy < s; ++dy)
    for (int dx = 0; dx < s; ++dx)
      sum += base[dy * 64 + dx];
  out[id] = sum / (float)(s * s);
}

// ---------------- fused depthwise 3x3 (dw + pos), SAME zero pad ----------------
__global__ __launch_bounds__(256) void dwconv_kernel(const float* __restrict__ xs,
    const float* __restrict__ dw_w, const float* __restrict__ dw_b,
    const float* __restrict__ pos_w, const float* __restrict__ pos_b,
    float* __restrict__ xdw, float* __restrict__ pos, int lgHs) {
  int Hs = 1 << lgHs;
  int Ns = Hs * Hs;
  int id = blockIdx.x * 256 + threadIdx.x;           // c * Ns + n
  int c = id >> (2 * lgHs);
  int n = id & (Ns - 1);
  int y = n >> lgHs, x = n & (Hs - 1);
  const float* w1 = dw_w + c * 9;
  const float* w2 = pos_w + c * 9;
  const float* src = xs + c * Ns;
  float s1 = dw_b[c], s2 = pos_b[c];
  #pragma unroll
  for (int ky = 0; ky < 3; ++ky) {
    int yy = y + ky - 1;
    bool yok = (yy >= 0) && (yy < Hs);
    #pragma unroll
    for (int kx = 0; kx < 3; ++kx) {
      int xx = x + kx - 1;
      bool ok = yok && (xx >= 0) && (xx < Hs);
      float v = ok ? src[yy * Hs + xx] : 0.f;
      s1 += v * w1[ky * 3 + kx];
      s2 += v * w2[ky * 3 + kx];
    }
  }
  xdw[id] = s1;
  pos[id] = s2;
}

// ---------------- fp32 tiled GEMM: C[M,N] = A[M,K]*B[K,N] + bias (+pos for q,k) ----
__global__ __launch_bounds__(256) void gemm_kernel(const float* __restrict__ A,
    const float* __restrict__ B, float* __restrict__ C,
    const float* __restrict__ bias, const float* __restrict__ pos,
    int M, int N, int K) {
  __shared__ __align__(16) float a_lds[16][64];
  __shared__ __align__(16) float b_lds[16][64];
  const int t = threadIdx.x;
  const int cb = blockIdx.x * 64;
  const int rb = blockIdx.y * 64;
  const int tr = (t >> 4) << 2, tc = (t & 15) << 2;
  const int ar = t >> 2, ak = (t & 3) << 2;
  const int bi = t << 2;
  const int bk = bi >> 6, bc = bi & 63;
  float acc[4][4] = {};
  for (int k0 = 0; k0 < K; k0 += 16) {
    float4 av4 = *(const float4*)(A + (rb + ar) * K + k0 + ak);
    float4 bv4 = *(const float4*)(B + (size_t)(k0 + bk) * N + cb + bc);
    __syncthreads();
    a_lds[ak + 0][ar] = av4.x;
    a_lds[ak + 1][ar] = av4.y;
    a_lds[ak + 2][ar] = av4.z;
    a_lds[ak + 3][ar] = av4.w;
    *(float4*)&b_lds[bk][bc] = bv4;
    __syncthreads();
    #pragma unroll
    for (int kk = 0; kk < 16; ++kk) {
      float4 a = *(const float4*)&a_lds[kk][tr];
      float4 b = *(const float4*)&b_lds[kk][tc];
      acc[0][0] += a.x * b.x; acc[0][1] += a.x * b.y; acc[0][2] += a.x * b.z; acc[0][3] += a.x * b.w;
      acc[1][0] += a.y * b.x; acc[1][1] += a.y * b.y; acc[1][2] += a.y * b.z; acc[1][3] += a.y * b.w;
      acc[2][0] += a.z * b.x; acc[2][1] += a.z * b.y; acc[2][2] += a.z * b.z; acc[2][3] += a.z * b.w;
      acc[3][0] += a.w * b.x; acc[3][1] += a.w * b.y; acc[3][2] += a.w * b.z; acc[3][3] += a.w * b.w;
    }
  }
  #pragma unroll
  for (int i = 0; i < 4; ++i) {
    int o = rb + tr + i;
    float bs = bias[o];
    float4 v;
    v.x = acc[i][0] + bs; v.y = acc[i][1] + bs; v.z = acc[i][2] + bs; v.w = acc[i][3] + bs;
    if (pos != nullptr && o < 2 * DIM) {
      const float* pr = pos + (size_t)(o & (DIM - 1)) * N + cb + tc;
      v.x += pr[0]; v.y += pr[1]; v.z += pr[2]; v.w += pr[3];
    }
    *(float4*)(C + (size_t)o * N + cb + tc) = v;
  }
}

// ---------------- attention via bf16 MFMA, S^T orientation ----------------
// qkv layout [768][Ns]: q rows 0..255, k rows 256..511, v rows 512..767 (head h -> +h*32)
// Block: 4 waves x 32 queries = 128 queries. m-chunks of 64.
// S^T = K^T(m x d) * Q(d x n) via mfma(A=ktfrag, B=qfrag).  C-layout: row=quad*4+reg, col=lane&15.
// PV:  out^T(d x n) = V(d x m) * P^T(m x n) via mfma(A=vfrag, B=ptfrag).
// P^T round-trips through wave-private LDS (packed b32 writes, b128 frag reads, no barrier).
__global__ __launch_bounds__(256) void attn_mfma_kernel(const float* __restrict__ qkv,
                                                        float* __restrict__ out, int Ns) {
  __shared__ unsigned short q_lds[128 * 40];        // Q^T bf16 [nn][d], pad 40
  __shared__ unsigned short kt_lds[64 * 40];        // K^T bf16 [mm][d], pad 40
  __shared__ unsigned short v_lds[32 * 72];         // V   bf16 [d][mm], pad 72
  __shared__ unsigned short pt_lds[4 * 32 * 72];    // P^T bf16 per wave [n][mm], pad 72
  const int t = threadIdx.x;
  const int h = blockIdx.y;
  const int n0 = blockIdx.x * 128;
  const int wave = t >> 6;
  const int lane = t & 63;
  const int ln = lane & 15;
  const int quad = lane >> 4;
  const float* qg = qkv + (size_t)(h * HD) * Ns;
  const float* kg = qkv + (size_t)(DIM + h * HD) * Ns;
  const float* vg = qkv + (size_t)(2 * DIM + h * HD) * Ns;

  // stage Q^T (pre-scaled by 1/sqrt(32)) as bf16
  #pragma unroll
  for (int i = 0; i < 16; ++i) {
    int idx = i * 256 + t;
    int d = idx >> 7, nn = idx & 127;
    q_lds[nn * 40 + d] = f2bf(qg[(size_t)d * Ns + n0 + nn] * 0.17677669529663689f);
  }
  __syncthreads();
  const int wn0 = wave * 32;
  bf16x8 qf0 = *(const bf16x8*)&q_lds[(wn0 + ln) * 40 + quad * 8];
  bf16x8 qf1 = *(const bf16x8*)&q_lds[(wn0 + 16 + ln) * 40 + quad * 8];

  f32x4 acc[2][2] = {};                             // [d-tile][n-tile]
  float lsum0 = 0.f, lsum1 = 0.f;
  unsigned short* ptw = pt_lds + wave * (32 * 72);
  const f32x4 zero = {0.f, 0.f, 0.f, 0.f};

  for (int m0 = 0; m0 < Ns; m0 += 64) {
    __syncthreads();                                // prior chunk's PV readers done
    #pragma unroll
    for (int i = 0; i < 2; ++i) {
      int idx4 = i * 256 + t;                       // 512 float4 = 32 rows x 64 cols
      int d = idx4 >> 4;
      int mm = (idx4 & 15) * 4;
      float4 k4 = *(const float4*)(kg + (size_t)d * Ns + m0 + mm);
      kt_lds[(mm + 0) * 40 + d] = f2bf(k4.x);
      kt_lds[(mm + 1) * 40 + d] = f2bf(k4.y);
      kt_lds[(mm + 2) * 40 + d] = f2bf(k4.z);
      kt_lds[(mm + 3) * 40 + d] = f2bf(k4.w);
      float4 v4 = *(const float4*)(vg + (size_t)d * Ns + m0 + mm);
      unsigned int p0 = ((unsigned)f2bf(v4.y) << 16) | f2bf(v4.x);
      unsigned int p1 = ((unsigned)f2bf(v4.w) << 16) | f2bf(v4.z);
      *(unsigned int*)&v_lds[d * 72 + mm] = p0;
      *(unsigned int*)&v_lds[d * 72 + mm + 2] = p1;
    }
    __syncthreads();

    // QK^T -> S^T tiles (4 m-tiles x 2 n-tiles)
    f32x4 s[4][2];
    #pragma unroll
    for (int mt = 0; mt < 4; ++mt) {
      bf16x8 ktf = *(const bf16x8*)&kt_lds[(mt * 16 + ln) * 40 + quad * 8];
      s[mt][0] = __builtin_amdgcn_mfma_f32_16x16x32_bf16(ktf, qf0, zero, 0, 0, 0);
      s[mt][1] = __builtin_amdgcn_mfma_f32_16x16x32_bf16(ktf, qf1, zero, 0, 0, 0);
    }
    // exp + row-sum partials + pack to bf16 P^T in wave-private LDS
    #pragma unroll
    for (int mt = 0; mt < 4; ++mt) {
      #pragma unroll
      for (int nt = 0; nt < 2; ++nt) {
        float e0 = __expf(s[mt][nt].x);
        float e1 = __expf(s[mt][nt].y);
        float e2 = __expf(s[mt][nt].z);
        float e3 = __expf(s[mt][nt].w);
        if (nt == 0) lsum0 += (e0 + e1) + (e2 + e3);
        else         lsum1 += (e0 + e1) + (e2 + e3);
        unsigned int p0 = ((unsigned)f2bf(e1) << 16) | f2bf(e0);
        unsigned int p1 = ((unsigned)f2bf(e3) << 16) | f2bf(e2);
        int row = nt * 16 + ln;
        int col = mt * 16 + quad * 4;               // m = quad*4+reg within tile
        *(unsigned int*)&ptw[row * 72 + col] = p0;
        *(unsigned int*)&ptw[row * 72 + col + 2] = p1;
      }
    }
    // PV: acc[dt][nt] += V(d x m32) * P^T(m32 x n16)
    #pragma unroll
    for (int ks = 0; ks < 2; ++ks) {
      bf16x8 ptf0 = *(const bf16x8*)&ptw[ln * 72 + ks * 32 + quad * 8];
      bf16x8 ptf1 = *(const bf16x8*)&ptw[(16 + ln) * 72 + ks * 32 + quad * 8];
      #pragma unroll
      for (int dt = 0; dt < 2; ++dt) {
        bf16x8 vf = *(const bf16x8*)&v_lds[(dt * 16 + ln) * 72 + ks * 32 + quad * 8];
        acc[dt][0] = __builtin_amdgcn_mfma_f32_16x16x32_bf16(vf, ptf0, acc[dt][0], 0, 0, 0);
        acc[dt][1] = __builtin_amdgcn_mfma_f32_16x16x32_bf16(vf, ptf1, acc[dt][1], 0, 0, 0);
      }
    }
  }
  // full row sums: reduce over quads (lanes ln, ln+16, ln+32, ln+48)
  lsum0 += __shfl_xor(lsum0, 16, 64);
  lsum0 += __shfl_xor(lsum0, 32, 64);
  lsum1 += __shfl_xor(lsum1, 16, 64);
  lsum1 += __shfl_xor(lsum1, 32, 64);
  float inv0 = 1.0f / lsum0, inv1 = 1.0f / lsum1;
  #pragma unroll
  for (int dt = 0; dt < 2; ++dt) {
    #pragma unroll
    for (int r = 0; r < 4; ++r) {
      int c = h * HD + dt * 16 + quad * 4 + r;
      out[(size_t)c * Ns + n0 + wn0 + ln]      = ((const float*)&acc[dt][0])[r] * inv0;
      out[(size_t)c * Ns + n0 + wn0 + 16 + ln] = ((const float*)&acc[dt][1])[r] * inv1;
    }
  }
}

// ---------------- bilinear upsample to 64x64 (jax half-pixel + edge clamp) -------
__global__ __launch_bounds__(256) void upsample_kernel(const float* __restrict__ src,
                                                       float* __restrict__ dst, int lgHs) {
  int Hs = 1 << lgHs;
  int id = blockIdx.x * 256 + threadIdx.x;           // c*4096 + y*64 + x
  int c = id >> 12, n = id & 4095;
  int y = n >> 6, x = n & 63;
  float sc = (float)Hs / 64.0f;
  float fy = ((float)y + 0.5f) * sc - 0.5f;
  float fx = ((float)x + 0.5f) * sc - 0.5f;
  float fy0 = floorf(fy), fx0 = floorf(fx);
  int y0 = (int)fy0, x0 = (int)fx0;
  float ty = fy - fy0, tx = fx - fx0;
  int y0c = min(max(y0, 0), Hs - 1), y1c = min(max(y0 + 1, 0), Hs - 1);
  int x0c = min(max(x0, 0), Hs - 1), x1c = min(max(x0 + 1, 0), Hs - 1);
  const float* s = src + c * Hs * Hs;
  float v00 = s[y0c * Hs + x0c], v01 = s[y0c * Hs + x1c];
  float v10 = s[y1c * Hs + x0c], v11 = s[y1c * Hs + x1c];
  float v0 = v00 + (v01 - v00) * tx;
  float v1 = v10 + (v11 - v10) * tx;
  dst[id] = v0 + (v1 - v0) * ty;
}

extern "C" void kernel_launch(void* const* d_in, const int* in_sizes, int n_in,
                              void* d_out, int out_size, void* d_ws, size_t ws_size,
                              hipStream_t stream) {
  const float* x     = (const float*)d_in[0];
  const float* dw_w  = (const float*)d_in[1];
  const float* dw_b  = (const float*)d_in[2];
  const float* pw_w  = (const float*)d_in[3];
  const float* pw_b  = (const float*)d_in[4];
  const float* pos_w = (const float*)d_in[5];
  const float* pos_b = (const float*)d_in[6];
  const float* fus_w = (const float*)d_in[7];
  const float* fus_b = (const float*)d_in[8];
  float* out = (float*)d_out;
  float* ws = (float*)d_ws;

  float* xs2  = ws;                  // 256*32*32
  float* xs4  = xs2 + 262144;        // 256*16*16
  float* xdw  = xs4 + 65536;         // 256*4096 (reused per scale)
  float* posb = xdw + 1048576;       // 256*4096 (reused per scale)
  float* qkv  = posb + 1048576;      // 768*4096 (reused per scale)
  float* cat  = qkv + 3145728;       // 768*4096
  float* out2 = cat + 3145728;       // 256*1024
  float* out4 = out2 + 262144;       // 256*256

  avgpool_kernel<<<1024, 256, 0, stream>>>(x, xs2, 1);
  avgpool_kernel<<<256, 256, 0, stream>>>(x, xs4, 2);

  // ---- scale 1 (Hs=64, Ns=4096); attention writes cat rows 0..255 ----
  dwconv_kernel<<<4096, 256, 0, stream>>>(x, dw_w, dw_b, pos_w, pos_b, xdw, posb, 6);
  gemm_kernel<<<dim3(64, 12), 256, 0, stream>>>(pw_w, xdw, qkv, pw_b, posb, 768, 4096, 256);
  attn_mfma_kernel<<<dim3(32, 8), 256, 0, stream>>>(qkv, cat, 4096);

  // ---- scale 2 (Hs=32, Ns=1024) ----
  dwconv_kernel<<<1024, 256, 0, stream>>>(xs2, dw_w + 2304, dw_b + 256, pos_w + 2304,
                                          pos_b + 256, xdw, posb, 5);
  gemm_kernel<<<dim3(16, 12), 256, 0, stream>>>(pw_w + 196608, xdw, qkv, pw_b + 768,
                                                posb, 768, 1024, 256);
  attn_mfma_kernel<<<dim3(8, 8), 256, 0, stream>>>(qkv, out2, 1024);

  // ---- scale 4 (Hs=16, Ns=256) ----
  dwconv_kernel<<<256, 256, 0, stream>>>(xs4, dw_w + 4608, dw_b + 512, pos_w + 4608,
                                         pos_b + 512, xdw, posb, 4);
  gemm_kernel<<<dim3(4, 12), 256, 0, stream>>>(pw_w + 393216, xdw, qkv, pw_b + 1536,
                                               posb, 768, 256, 256);
  attn_mfma_kernel<<<dim3(2, 8), 256, 0, stream>>>(qkv, out4, 256);

  // ---- upsample into cat rows 256..511 and 512..767 ----
  upsample_kernel<<<4096, 256, 0, stream>>>(out2, cat + 256 * 4096, 5);
  upsample_kernel<<<4096, 256, 0, stream>>>(out4, cat + 512 * 4096, 4);

  // ---- fusion GEMM: out[256][4096] = fusion_w[256][768] * cat[768][4096] + b ----
  gemm_kernel<<<dim3(64, 4), 256, 0, stream>>>(fus_w, cat, out, fus_b, nullptr,
                                               256, 4096, 768);
}

// Round 3
// 300.851 us; speedup vs baseline: 2.3061x; 1.3210x over previous
//
#include <hip/hip_runtime.h>
#include <math.h>

#define DIM 256
#define HEADS 8
#define HD 32

typedef __attribute__((ext_vector_type(8))) short bf16x8;
typedef __attribute__((ext_vector_type(4))) float f32x4;

__device__ __forceinline__ unsigned short f2bf(float f) {
  unsigned int u = __float_as_uint(f);
  unsigned int r = u + 0x7fff + ((u >> 16) & 1);   // round-to-nearest-even
  return (unsigned short)(r >> 16);
}

// ---------------- avg pool (from 256x64x64) ----------------
__global__ __launch_bounds__(256) void avgpool_kernel(const float* __restrict__ x,
                                                      float* __restrict__ out, int lgS) {
  int s = 1 << lgS;
  int lgHs = 6 - lgS;
  int Hs = 1 << lgHs;
  int id = blockIdx.x * 256 + threadIdx.x;           // c * Ns + n
  int c = id >> (2 * lgHs);
  int n = id & ((1 << (2 * lgHs)) - 1);
  int y = (n >> lgHs) << lgS;
  int x0 = (n & (Hs - 1)) << lgS;
  const float* base = x + c * 4096 + y * 64 + x0;
  float sum = 0.f;
  for (int dy = 0; dy < s; ++dy)
    for (int dx = 0; dx < s; ++dx)
      sum += base[dy * 64 + dx];
  out[id] = sum / (float)(s * s);
}

// ---------------- fused depthwise 3x3 (dw + pos), SAME zero pad ----------------
__global__ __launch_bounds__(256) void dwconv_kernel(const float* __restrict__ xs,
    const float* __restrict__ dw_w, const float* __restrict__ dw_b,
    const float* __restrict__ pos_w, const float* __restrict__ pos_b,
    float* __restrict__ xdw, float* __restrict__ pos, int lgHs) {
  int Hs = 1 << lgHs;
  int Ns = Hs * Hs;
  int id = blockIdx.x * 256 + threadIdx.x;           // c * Ns + n
  int c = id >> (2 * lgHs);
  int n = id & (Ns - 1);
  int y = n >> lgHs, x = n & (Hs - 1);
  const float* w1 = dw_w + c * 9;
  const float* w2 = pos_w + c * 9;
  const float* src = xs + c * Ns;
  float s1 = dw_b[c], s2 = pos_b[c];
  #pragma unroll
  for (int ky = 0; ky < 3; ++ky) {
    int yy = y + ky - 1;
    bool yok = (yy >= 0) && (yy < Hs);
    #pragma unroll
    for (int kx = 0; kx < 3; ++kx) {
      int xx = x + kx - 1;
      bool ok = yok && (xx >= 0) && (xx < Hs);
      float v = ok ? src[yy * Hs + xx] : 0.f;
      s1 += v * w1[ky * 3 + kx];
      s2 += v * w2[ky * 3 + kx];
    }
  }
  xdw[id] = s1;
  pos[id] = s2;
}

// ---------------- fp32 tiled GEMM (channel-major) for the fusion layer ----------
__global__ __launch_bounds__(256) void gemm_kernel(const float* __restrict__ A,
    const float* __restrict__ B, float* __restrict__ C,
    const float* __restrict__ bias, int M, int N, int K) {
  __shared__ __align__(16) float a_lds[16][64];
  __shared__ __align__(16) float b_lds[16][64];
  const int t = threadIdx.x;
  const int cb = blockIdx.x * 64;
  const int rb = blockIdx.y * 64;
  const int tr = (t >> 4) << 2, tc = (t & 15) << 2;
  const int ar = t >> 2, ak = (t & 3) << 2;
  const int bi = t << 2;
  const int bk = bi >> 6, bc = bi & 63;
  float acc[4][4] = {};
  for (int k0 = 0; k0 < K; k0 += 16) {
    float4 av4 = *(const float4*)(A + (rb + ar) * K + k0 + ak);
    float4 bv4 = *(const float4*)(B + (size_t)(k0 + bk) * N + cb + bc);
    __syncthreads();
    a_lds[ak + 0][ar] = av4.x;
    a_lds[ak + 1][ar] = av4.y;
    a_lds[ak + 2][ar] = av4.z;
    a_lds[ak + 3][ar] = av4.w;
    *(float4*)&b_lds[bk][bc] = bv4;
    __syncthreads();
    #pragma unroll
    for (int kk = 0; kk < 16; ++kk) {
      float4 a = *(const float4*)&a_lds[kk][tr];
      float4 b = *(const float4*)&b_lds[kk][tc];
      acc[0][0] += a.x * b.x; acc[0][1] += a.x * b.y; acc[0][2] += a.x * b.z; acc[0][3] += a.x * b.w;
      acc[1][0] += a.y * b.x; acc[1][1] += a.y * b.y; acc[1][2] += a.y * b.z; acc[1][3] += a.y * b.w;
      acc[2][0] += a.z * b.x; acc[2][1] += a.z * b.y; acc[2][2] += a.z * b.z; acc[2][3] += a.z * b.w;
      acc[3][0] += a.w * b.x; acc[3][1] += a.w * b.y; acc[3][2] += a.w * b.z; acc[3][3] += a.w * b.w;
    }
  }
  #pragma unroll
  for (int i = 0; i < 4; ++i) {
    int o = rb + tr + i;
    float bs = bias[o];
    float4 v;
    v.x = acc[i][0] + bs; v.y = acc[i][1] + bs; v.z = acc[i][2] + bs; v.w = acc[i][3] + bs;
    *(float4*)(C + (size_t)o * N + cb + tc) = v;
  }
}

// ---------------- spatial-major QKV GEMM with bf16 MFMA-layout outputs ----------
// C[n][o] = sum_c xdw[c][n] * W[o][c] + bias[o]  (n = spatial, o = channel 0..767)
// o <  256: q -> qkvT[n][o]     bf16, (val + pos) * 1/sqrt(32)
// o <  512: k -> qkvT[n][o]     bf16, (val + pos)
// o >= 512: v -> Vb[o-512][n]   bf16
__global__ __launch_bounds__(256) void gemm_qkvT_kernel(const float* __restrict__ xdw,
    const float* __restrict__ W, const float* __restrict__ bias,
    const float* __restrict__ pos, unsigned short* __restrict__ qkvT,
    unsigned short* __restrict__ Vb, int Ns) {
  __shared__ __align__(16) float a_lds[16][64];     // [c][n]
  __shared__ __align__(16) float b_lds[16][64];     // [c][o]
  const int t = threadIdx.x;
  const int cb = blockIdx.x * 64;                   // o-range
  const int rb = blockIdx.y * 64;                   // n-range
  const int tr = (t >> 4) << 2, tc = (t & 15) << 2;
  const int ac = t >> 4, an = (t & 15) << 2;        // A stage: c-row, n-col4
  const int wo = t >> 2, wc = (t & 3) << 2;         // W stage: o-row, c-col4
  float acc[4][4] = {};                             // [n-row][o-col]
  for (int k0 = 0; k0 < 256; k0 += 16) {
    float4 av4 = *(const float4*)(xdw + (size_t)(k0 + ac) * Ns + rb + an);
    float4 wv4 = *(const float4*)(W + (size_t)(cb + wo) * 256 + k0 + wc);
    __syncthreads();
    *(float4*)&a_lds[ac][an] = av4;
    b_lds[wc + 0][wo] = wv4.x;
    b_lds[wc + 1][wo] = wv4.y;
    b_lds[wc + 2][wo] = wv4.z;
    b_lds[wc + 3][wo] = wv4.w;
    __syncthreads();
    #pragma unroll
    for (int kk = 0; kk < 16; ++kk) {
      float4 a = *(const float4*)&a_lds[kk][tr];
      float4 b = *(const float4*)&b_lds[kk][tc];
      acc[0][0] += a.x * b.x; acc[0][1] += a.x * b.y; acc[0][2] += a.x * b.z; acc[0][3] += a.x * b.w;
      acc[1][0] += a.y * b.x; acc[1][1] += a.y * b.y; acc[1][2] += a.y * b.z; acc[1][3] += a.y * b.w;
      acc[2][0] += a.z * b.x; acc[2][1] += a.z * b.y; acc[2][2] += a.z * b.z; acc[2][3] += a.z * b.w;
      acc[3][0] += a.w * b.x; acc[3][1] += a.w * b.y; acc[3][2] += a.w * b.z; acc[3][3] += a.w * b.w;
    }
  }
  if (cb < 512) {                                   // q or k tile (uniform per block)
    const bool isq = cb < 256;
    const int cpos = cb & 255;
    float4 p[4];
    #pragma unroll
    for (int j = 0; j < 4; ++j)
      p[j] = *(const float4*)(pos + (size_t)(cpos + tc + j) * Ns + rb + tr);
    #pragma unroll
    for (int i = 0; i < 4; ++i) {
      ushort4 st;
      float v0 = acc[i][0] + bias[cb + tc + 0] + ((const float*)&p[0])[i];
      float v1 = acc[i][1] + bias[cb + tc + 1] + ((const float*)&p[1])[i];
      float v2 = acc[i][2] + bias[cb + tc + 2] + ((const float*)&p[2])[i];
      float v3 = acc[i][3] + bias[cb + tc + 3] + ((const float*)&p[3])[i];
      if (isq) {
        v0 *= 0.17677669529663689f; v1 *= 0.17677669529663689f;
        v2 *= 0.17677669529663689f; v3 *= 0.17677669529663689f;
      }
      st.x = f2bf(v0); st.y = f2bf(v1); st.z = f2bf(v2); st.w = f2bf(v3);
      *(ushort4*)(qkvT + (size_t)(rb + tr + i) * 512 + cb + tc) = st;
    }
  } else {                                          // v tile -> Vb[c][n]
    #pragma unroll
    for (int j = 0; j < 4; ++j) {
      int c = cb + tc + j - 512;
      float bs = bias[cb + tc + j];
      ushort4 st;
      st.x = f2bf(acc[0][j] + bs);
      st.y = f2bf(acc[1][j] + bs);
      st.z = f2bf(acc[2][j] + bs);
      st.w = f2bf(acc[3][j] + bs);
      *(ushort4*)(Vb + (size_t)c * Ns + rb + tr) = st;
    }
  }
}

// ---------------- attention v2: barrier-free, direct global fragments -----------
// qkvT [Ns][512] bf16 (q cols 0..255 pre-scaled+pos, k cols 256..511 +pos)
// Vb   [256][Ns] bf16 (row = h*32+d)
// grid (qtiles, heads, 4 kv-splits); block 256 = 4 waves x 32 queries.
// Partials: accp[sp][c][Ns] (unnormalized PV sums), lsump[sp][h][Ns].
__global__ __launch_bounds__(256) void attn2_kernel(const unsigned short* __restrict__ qkvT,
    const unsigned short* __restrict__ Vb, float* __restrict__ accp,
    float* __restrict__ lsump, int Ns, int lgMs) {
  __shared__ unsigned short pt_lds[4 * 32 * 72];    // wave-private P^T [n][m], pad 72
  const int t = threadIdx.x;
  const int wave = t >> 6, lane = t & 63;
  const int ln = lane & 15, quad = lane >> 4;
  const int h = blockIdx.y, sp = blockIdx.z;
  const int n0 = blockIdx.x * 128 + wave * 32;
  const unsigned short* qb = qkvT + (size_t)n0 * 512 + h * 32 + quad * 8;
  bf16x8 qf0 = *(const bf16x8*)(qb + (size_t)ln * 512);
  bf16x8 qf1 = *(const bf16x8*)(qb + (size_t)(16 + ln) * 512);
  unsigned short* ptw = pt_lds + wave * (32 * 72);
  f32x4 acc[2][2] = {};                             // [d-tile][n-tile]
  float lsum0 = 0.f, lsum1 = 0.f;
  const f32x4 zero = {0.f, 0.f, 0.f, 0.f};
  const int m0s = sp << lgMs;
  const int nch = 1 << (lgMs - 6);
  const unsigned short* kb = qkvT + (size_t)(m0s + ln) * 512 + 256 + h * 32 + quad * 8;
  const unsigned short* vb = Vb + (size_t)(h * 32 + ln) * Ns + m0s + quad * 8;
  for (int ch = 0; ch < nch; ++ch) {
    const unsigned short* kc = kb + (size_t)ch * 64 * 512;
    const unsigned short* vc = vb + ch * 64;
    // issue all global loads up front (no barriers anywhere -> deep overlap)
    bf16x8 kf0 = *(const bf16x8*)(kc);
    bf16x8 kf1 = *(const bf16x8*)(kc + 16 * 512);
    bf16x8 kf2 = *(const bf16x8*)(kc + 32 * 512);
    bf16x8 kf3 = *(const bf16x8*)(kc + 48 * 512);
    bf16x8 vf00 = *(const bf16x8*)(vc);
    bf16x8 vf01 = *(const bf16x8*)(vc + 32);
    bf16x8 vf10 = *(const bf16x8*)(vc + (size_t)16 * Ns);
    bf16x8 vf11 = *(const bf16x8*)(vc + (size_t)16 * Ns + 32);
    f32x4 s[4][2];
    s[0][0] = __builtin_amdgcn_mfma_f32_16x16x32_bf16(kf0, qf0, zero, 0, 0, 0);
    s[0][1] = __builtin_amdgcn_mfma_f32_16x16x32_bf16(kf0, qf1, zero, 0, 0, 0);
    s[1][0] = __builtin_amdgcn_mfma_f32_16x16x32_bf16(kf1, qf0, zero, 0, 0, 0);
    s[1][1] = __builtin_amdgcn_mfma_f32_16x16x32_bf16(kf1, qf1, zero, 0, 0, 0);
    s[2][0] = __builtin_amdgcn_mfma_f32_16x16x32_bf16(kf2, qf0, zero, 0, 0, 0);
    s[2][1] = __builtin_amdgcn_mfma_f32_16x16x32_bf16(kf2, qf1, zero, 0, 0, 0);
    s[3][0] = __builtin_amdgcn_mfma_f32_16x16x32_bf16(kf3, qf0, zero, 0, 0, 0);
    s[3][1] = __builtin_amdgcn_mfma_f32_16x16x32_bf16(kf3, qf1, zero, 0, 0, 0);
    #pragma unroll
    for (int mt = 0; mt < 4; ++mt) {
      #pragma unroll
      for (int nt = 0; nt < 2; ++nt) {
        float e0 = __expf(s[mt][nt].x);
        float e1 = __expf(s[mt][nt].y);
        float e2 = __expf(s[mt][nt].z);
        float e3 = __expf(s[mt][nt].w);
        if (nt == 0) lsum0 += (e0 + e1) + (e2 + e3);
        else         lsum1 += (e0 + e1) + (e2 + e3);
        uint2 pk;
        pk.x = ((unsigned)f2bf(e1) << 16) | f2bf(e0);
        pk.y = ((unsigned)f2bf(e3) << 16) | f2bf(e2);
        *(uint2*)&ptw[(nt * 16 + ln) * 72 + mt * 16 + quad * 4] = pk;
      }
    }
    #pragma unroll
    for (int ks = 0; ks < 2; ++ks) {
      bf16x8 pf0 = *(const bf16x8*)&ptw[ln * 72 + ks * 32 + quad * 8];
      bf16x8 pf1 = *(const bf16x8*)&ptw[(16 + ln) * 72 + ks * 32 + quad * 8];
      bf16x8 va = ks ? vf01 : vf00;
      bf16x8 vbf = ks ? vf11 : vf10;
      acc[0][0] = __builtin_amdgcn_mfma_f32_16x16x32_bf16(va, pf0, acc[0][0], 0, 0, 0);
      acc[0][1] = __builtin_amdgcn_mfma_f32_16x16x32_bf16(va, pf1, acc[0][1], 0, 0, 0);
      acc[1][0] = __builtin_amdgcn_mfma_f32_16x16x32_bf16(vbf, pf0, acc[1][0], 0, 0, 0);
      acc[1][1] = __builtin_amdgcn_mfma_f32_16x16x32_bf16(vbf, pf1, acc[1][1], 0, 0, 0);
    }
  }
  lsum0 += __shfl_xor(lsum0, 16, 64);
  lsum0 += __shfl_xor(lsum0, 32, 64);
  lsum1 += __shfl_xor(lsum1, 16, 64);
  lsum1 += __shfl_xor(lsum1, 32, 64);
  float* ap = accp + ((size_t)sp * 256 + h * 32) * Ns;
  #pragma unroll
  for (int dt = 0; dt < 2; ++dt) {
    #pragma unroll
    for (int r = 0; r < 4; ++r) {
      int cl = dt * 16 + quad * 4 + r;
      ap[(size_t)cl * Ns + n0 + ln]      = ((const float*)&acc[dt][0])[r];
      ap[(size_t)cl * Ns + n0 + 16 + ln] = ((const float*)&acc[dt][1])[r];
    }
  }
  if (lane < 16) {
    float* lp = lsump + ((size_t)sp * 8 + h) * Ns + n0;
    lp[lane]      = lsum0;
    lp[16 + lane] = lsum1;
  }
}

// ---------------- combine kv-split partials: out = sum(acc) / sum(lsum) ---------
__global__ __launch_bounds__(256) void combine_kernel(const float* __restrict__ accp,
    const float* __restrict__ lsump, float* __restrict__ out, int lgNs) {
  int id = blockIdx.x * 256 + threadIdx.x;          // c*Ns + n
  int Ns = 1 << lgNs;
  int n = id & (Ns - 1);
  int h = id >> (lgNs + 5);
  int sA = 256 << lgNs;
  int sL = 8 << lgNs;
  float v = accp[id] + accp[id + sA] + accp[id + 2 * sA] + accp[id + 3 * sA];
  int li = (h << lgNs) + n;
  float d = lsump[li] + lsump[li + sL] + lsump[li + 2 * sL] + lsump[li + 3 * sL];
  out[id] = v / d;
}

// ---------------- bilinear upsample to 64x64 (jax half-pixel + edge clamp) -------
__global__ __launch_bounds__(256) void upsample_kernel(const float* __restrict__ src,
                                                       float* __restrict__ dst, int lgHs) {
  int Hs = 1 << lgHs;
  int id = blockIdx.x * 256 + threadIdx.x;           // c*4096 + y*64 + x
  int c = id >> 12, n = id & 4095;
  int y = n >> 6, x = n & 63;
  float sc = (float)Hs / 64.0f;
  float fy = ((float)y + 0.5f) * sc - 0.5f;
  float fx = ((float)x + 0.5f) * sc - 0.5f;
  float fy0 = floorf(fy), fx0 = floorf(fx);
  int y0 = (int)fy0, x0 = (int)fx0;
  float ty = fy - fy0, tx = fx - fx0;
  int y0c = min(max(y0, 0), Hs - 1), y1c = min(max(y0 + 1, 0), Hs - 1);
  int x0c = min(max(x0, 0), Hs - 1), x1c = min(max(x0 + 1, 0), Hs - 1);
  const float* s = src + c * Hs * Hs;
  float v00 = s[y0c * Hs + x0c], v01 = s[y0c * Hs + x1c];
  float v10 = s[y1c * Hs + x0c], v11 = s[y1c * Hs + x1c];
  float v0 = v00 + (v01 - v00) * tx;
  float v1 = v10 + (v11 - v10) * tx;
  dst[id] = v0 + (v1 - v0) * ty;
}

extern "C" void kernel_launch(void* const* d_in, const int* in_sizes, int n_in,
                              void* d_out, int out_size, void* d_ws, size_t ws_size,
                              hipStream_t stream) {
  const float* x     = (const float*)d_in[0];
  const float* dw_w  = (const float*)d_in[1];
  const float* dw_b  = (const float*)d_in[2];
  const float* pw_w  = (const float*)d_in[3];
  const float* pw_b  = (const float*)d_in[4];
  const float* pos_w = (const float*)d_in[5];
  const float* pos_b = (const float*)d_in[6];
  const float* fus_w = (const float*)d_in[7];
  const float* fus_b = (const float*)d_in[8];
  float* out = (float*)d_out;
  float* ws = (float*)d_ws;

  // workspace layout (floats), total 11,796,480 (~47.2 MB)
  float* xs2   = ws;                         // 262,144
  float* xs4   = xs2 + 262144;               // 65,536
  float* xdw   = xs4 + 65536;                // 1,048,576
  float* posb  = xdw + 1048576;              // 1,048,576
  unsigned short* qkvT = (unsigned short*)(posb + 1048576);  // 2,097,152 shorts
  unsigned short* Vb   = (unsigned short*)(posb + 2097152);  // 1,048,576 shorts
  float* accp  = posb + 2621440;             // 4,194,304
  float* lsump = accp + 4194304;             // 131,072
  float* cat   = lsump + 131072;             // 3,145,728
  float* out2  = cat + 3145728;              // 262,144
  float* out4  = out2 + 262144;              // 65,536

  avgpool_kernel<<<1024, 256, 0, stream>>>(x, xs2, 1);
  avgpool_kernel<<<256, 256, 0, stream>>>(x, xs4, 2);

  // ---- scale 1 (Hs=64, Ns=4096) -> cat rows 0..255 ----
  dwconv_kernel<<<4096, 256, 0, stream>>>(x, dw_w, dw_b, pos_w, pos_b, xdw, posb, 6);
  gemm_qkvT_kernel<<<dim3(12, 64), 256, 0, stream>>>(xdw, pw_w, pw_b, posb, qkvT, Vb, 4096);
  attn2_kernel<<<dim3(32, 8, 4), 256, 0, stream>>>(qkvT, Vb, accp, lsump, 4096, 10);
  combine_kernel<<<4096, 256, 0, stream>>>(accp, lsump, cat, 12);

  // ---- scale 2 (Hs=32, Ns=1024) ----
  dwconv_kernel<<<1024, 256, 0, stream>>>(xs2, dw_w + 2304, dw_b + 256, pos_w + 2304,
                                          pos_b + 256, xdw, posb, 5);
  gemm_qkvT_kernel<<<dim3(12, 16), 256, 0, stream>>>(xdw, pw_w + 196608, pw_b + 768,
                                                     posb, qkvT, Vb, 1024);
  attn2_kernel<<<dim3(8, 8, 4), 256, 0, stream>>>(qkvT, Vb, accp, lsump, 1024, 8);
  combine_kernel<<<1024, 256, 0, stream>>>(accp, lsump, out2, 10);

  // ---- scale 4 (Hs=16, Ns=256) ----
  dwconv_kernel<<<256, 256, 0, stream>>>(xs4, dw_w + 4608, dw_b + 512, pos_w + 4608,
                                         pos_b + 512, xdw, posb, 4);
  gemm_qkvT_kernel<<<dim3(12, 4), 256, 0, stream>>>(xdw, pw_w + 393216, pw_b + 1536,
                                                    posb, qkvT, Vb, 256);
  attn2_kernel<<<dim3(2, 8, 4), 256, 0, stream>>>(qkvT, Vb, accp, lsump, 256, 6);
  combine_kernel<<<256, 256, 0, stream>>>(accp, lsump, out4, 8);

  // ---- upsample into cat rows 256..511 and 512..767 ----
  upsample_kernel<<<4096, 256, 0, stream>>>(out2, cat + 256 * 4096, 5);
  upsample_kernel<<<4096, 256, 0, stream>>>(out4, cat + 512 * 4096, 4);

  // ---- fusion GEMM: out[256][4096] = fusion_w[256][768] * cat[768][4096] + b ----
  gemm_kernel<<<dim3(64, 4), 256, 0, stream>>>(fus_w, cat, out, fus_b, 256, 4096, 768);
}

// Round 4
// 248.811 us; speedup vs baseline: 2.7885x; 1.2092x over previous
//
#include <hip/hip_runtime.h>
#include <math.h>

#define DIM 256
#define HEADS 8
#define HD 32
// log2(e)/sqrt(32): folded into stored Q so attention uses native exp2
#define QSCALE 0.25504526770295183f

typedef __attribute__((ext_vector_type(8))) short bf16x8;
typedef __attribute__((ext_vector_type(4))) float f32x4;

#if __has_builtin(__builtin_amdgcn_exp2f)
#define EXP2(x) __builtin_amdgcn_exp2f(x)
#else
#define EXP2(x) __expf((x) * 0.6931471805599453f)
#endif

__device__ __forceinline__ unsigned short f2bf(float f) {
  unsigned int u = __float_as_uint(f);
  unsigned int r = u + 0x7fff + ((u >> 16) & 1);   // round-to-nearest-even
  return (unsigned short)(r >> 16);
}
__device__ __forceinline__ float bf2f(unsigned short u) {
  return __uint_as_float(((unsigned int)u) << 16);
}

// ---------------- avg pool (from 256x64x64) ----------------
__global__ __launch_bounds__(256) void avgpool_kernel(const float* __restrict__ x,
                                                      float* __restrict__ out, int lgS) {
  int s = 1 << lgS;
  int lgHs = 6 - lgS;
  int Hs = 1 << lgHs;
  int id = blockIdx.x * 256 + threadIdx.x;
  int c = id >> (2 * lgHs);
  int n = id & ((1 << (2 * lgHs)) - 1);
  int y = (n >> lgHs) << lgS;
  int x0 = (n & (Hs - 1)) << lgS;
  const float* base = x + c * 4096 + y * 64 + x0;
  float sum = 0.f;
  for (int dy = 0; dy < s; ++dy)
    for (int dx = 0; dx < s; ++dx)
      sum += base[dy * 64 + dx];
  out[id] = sum / (float)(s * s);
}

// ---------------- fused depthwise 3x3 (dw + pos), SAME zero pad ----------------
__global__ __launch_bounds__(256) void dwconv_kernel(const float* __restrict__ xs,
    const float* __restrict__ dw_w, const float* __restrict__ dw_b,
    const float* __restrict__ pos_w, const float* __restrict__ pos_b,
    float* __restrict__ xdw, float* __restrict__ pos, int lgHs) {
  int Hs = 1 << lgHs;
  int Ns = Hs * Hs;
  int id = blockIdx.x * 256 + threadIdx.x;
  int c = id >> (2 * lgHs);
  int n = id & (Ns - 1);
  int y = n >> lgHs, x = n & (Hs - 1);
  const float* w1 = dw_w + c * 9;
  const float* w2 = pos_w + c * 9;
  const float* src = xs + c * Ns;
  float s1 = dw_b[c], s2 = pos_b[c];
  #pragma unroll
  for (int ky = 0; ky < 3; ++ky) {
    int yy = y + ky - 1;
    bool yok = (yy >= 0) && (yy < Hs);
    #pragma unroll
    for (int kx = 0; kx < 3; ++kx) {
      int xx = x + kx - 1;
      bool ok = yok && (xx >= 0) && (xx < Hs);
      float v = ok ? src[yy * Hs + xx] : 0.f;
      s1 += v * w1[ky * 3 + kx];
      s2 += v * w2[ky * 3 + kx];
    }
  }
  xdw[id] = s1;
  pos[id] = s2;
}

// ---------------- plain fp32 -> bf16 cvt (weights) ----------------
__global__ __launch_bounds__(256) void cvt_kernel(const float* __restrict__ src,
                                                  unsigned short* __restrict__ dst) {
  int id = blockIdx.x * 256 + threadIdx.x;          // one float4 per thread
  float4 v = *(const float4*)(src + id * 4);
  ushort4 st;
  st.x = f2bf(v.x); st.y = f2bf(v.y); st.z = f2bf(v.z); st.w = f2bf(v.w);
  *(ushort4*)(dst + id * 4) = st;
}

// ---------------- transpose + cvt: src fp32 [C][N] -> dst bf16 [N][C] ----------
// grid (N/64, C/64), 64x64 tiles via LDS.
__global__ __launch_bounds__(256) void transpose_cvt_kernel(const float* __restrict__ src,
    unsigned short* __restrict__ dst, int C, int N) {
  __shared__ unsigned short lds[64][72];
  const int t = threadIdx.x;
  const int n0 = blockIdx.x * 64, c0 = blockIdx.y * 64;
  #pragma unroll
  for (int p = 0; p < 4; ++p) {
    int c = p * 16 + (t >> 4);
    int nn = (t & 15) * 4;
    float4 v = *(const float4*)(src + (size_t)(c0 + c) * N + n0 + nn);
    lds[nn + 0][c] = f2bf(v.x);
    lds[nn + 1][c] = f2bf(v.y);
    lds[nn + 2][c] = f2bf(v.z);
    lds[nn + 3][c] = f2bf(v.w);
  }
  __syncthreads();
  int n = t >> 2, seg = (t & 3) * 16;
  *(bf16x8*)(dst + (size_t)(n0 + n) * C + c0 + seg)     = *(const bf16x8*)&lds[n][seg];
  *(bf16x8*)(dst + (size_t)(n0 + n) * C + c0 + seg + 8) = *(const bf16x8*)&lds[n][seg + 8];
}

// ---------------- QKV GEMM via bf16 MFMA, barrier-free -------------------------
// Wb bf16 [768][256], xdwT bf16 [Ns][256], posT bf16 [Ns][256].
// D[o][n] = sum_c Wb[o][c]*xdwT[n][c].  Block 64o x 64n (4 waves, 32x32 each).
// o<256: q -> qkvT[n][o] = (D+bias+pos)*QSCALE ; o<512: k -> qkvT[n][o] = D+bias+pos
// o>=512: v -> Vb[o-512][n] = D+bias
__global__ __launch_bounds__(256) void gemm_qkv_mfma(const unsigned short* __restrict__ Wb,
    const unsigned short* __restrict__ xdwT, const float* __restrict__ bias,
    const unsigned short* __restrict__ posT, unsigned short* __restrict__ qkvT,
    unsigned short* __restrict__ Vb, int Ns) {
  const int t = threadIdx.x;
  const int wave = t >> 6, lane = t & 63;
  const int ln = lane & 15, quad = lane >> 4;
  const int o0 = blockIdx.x * 64 + (wave & 1) * 32;
  const int n0 = blockIdx.y * 64 + (wave >> 1) * 32;
  const unsigned short* a0 = Wb + (size_t)(o0 + ln) * 256 + quad * 8;
  const unsigned short* a1 = a0 + 16 * 256;
  const unsigned short* b0 = xdwT + (size_t)(n0 + ln) * 256 + quad * 8;
  const unsigned short* b1 = b0 + 16 * 256;
  f32x4 acc[2][2] = {};
  #pragma unroll
  for (int ks = 0; ks < 8; ++ks) {
    bf16x8 af0 = *(const bf16x8*)(a0 + ks * 32);
    bf16x8 af1 = *(const bf16x8*)(a1 + ks * 32);
    bf16x8 bv0 = *(const bf16x8*)(b0 + ks * 32);
    bf16x8 bv1 = *(const bf16x8*)(b1 + ks * 32);
    acc[0][0] = __builtin_amdgcn_mfma_f32_16x16x32_bf16(af0, bv0, acc[0][0], 0, 0, 0);
    acc[0][1] = __builtin_amdgcn_mfma_f32_16x16x32_bf16(af0, bv1, acc[0][1], 0, 0, 0);
    acc[1][0] = __builtin_amdgcn_mfma_f32_16x16x32_bf16(af1, bv0, acc[1][0], 0, 0, 0);
    acc[1][1] = __builtin_amdgcn_mfma_f32_16x16x32_bf16(af1, bv1, acc[1][1], 0, 0, 0);
  }
  const int cat = blockIdx.x >> 2;                  // 0=q 1=k 2=v
  #pragma unroll
  for (int mt = 0; mt < 2; ++mt) {
    int ot = o0 + mt * 16 + quad * 4;
    float bs0 = bias[ot], bs1 = bias[ot + 1], bs2 = bias[ot + 2], bs3 = bias[ot + 3];
    #pragma unroll
    for (int nt = 0; nt < 2; ++nt) {
      int nn = n0 + nt * 16 + ln;
      f32x4 v = acc[mt][nt];
      v.x += bs0; v.y += bs1; v.z += bs2; v.w += bs3;
      if (cat < 2) {
        ushort4 p4 = *(const ushort4*)(posT + (size_t)nn * 256 + (ot & 255));
        v.x += bf2f(p4.x); v.y += bf2f(p4.y); v.z += bf2f(p4.z); v.w += bf2f(p4.w);
        if (cat == 0) { v.x *= QSCALE; v.y *= QSCALE; v.z *= QSCALE; v.w *= QSCALE; }
        ushort4 st;
        st.x = f2bf(v.x); st.y = f2bf(v.y); st.z = f2bf(v.z); st.w = f2bf(v.w);
        *(ushort4*)(qkvT + (size_t)nn * 512 + ot) = st;
      } else {
        Vb[(size_t)(ot - 512 + 0) * Ns + nn] = f2bf(v.x);
        Vb[(size_t)(ot - 512 + 1) * Ns + nn] = f2bf(v.y);
        Vb[(size_t)(ot - 512 + 2) * Ns + nn] = f2bf(v.z);
        Vb[(size_t)(ot - 512 + 3) * Ns + nn] = f2bf(v.w);
      }
    }
  }
}

// ---------------- attention: barrier-free, direct global fragments -------------
// qkvT [Ns][512] bf16 (q pre-scaled by QSCALE incl. pos; k +pos), Vb [256][Ns] bf16
// grid (qtiles, heads, 4 kv-splits); block 256 = 4 waves x 32 queries.
__global__ __launch_bounds__(256) void attn2_kernel(const unsigned short* __restrict__ qkvT,
    const unsigned short* __restrict__ Vb, float* __restrict__ accp,
    float* __restrict__ lsump, int Ns, int lgMs) {
  __shared__ unsigned short pt_lds[4 * 32 * 72];    // wave-private P^T [n][m], pad 72
  const int t = threadIdx.x;
  const int wave = t >> 6, lane = t & 63;
  const int ln = lane & 15, quad = lane >> 4;
  const int h = blockIdx.y, sp = blockIdx.z;
  const int n0 = blockIdx.x * 128 + wave * 32;
  const unsigned short* qb = qkvT + (size_t)n0 * 512 + h * 32 + quad * 8;
  bf16x8 qf0 = *(const bf16x8*)(qb + (size_t)ln * 512);
  bf16x8 qf1 = *(const bf16x8*)(qb + (size_t)(16 + ln) * 512);
  unsigned short* ptw = pt_lds + wave * (32 * 72);
  f32x4 acc[2][2] = {};
  float lsum0 = 0.f, lsum1 = 0.f;
  const f32x4 zero = {0.f, 0.f, 0.f, 0.f};
  const int m0s = sp << lgMs;
  const int nch = 1 << (lgMs - 6);
  const unsigned short* kb = qkvT + (size_t)(m0s + ln) * 512 + 256 + h * 32 + quad * 8;
  const unsigned short* vb = Vb + (size_t)(h * 32 + ln) * Ns + m0s + quad * 8;
  for (int ch = 0; ch < nch; ++ch) {
    const unsigned short* kc = kb + (size_t)ch * 64 * 512;
    const unsigned short* vc = vb + ch * 64;
    bf16x8 kf0 = *(const bf16x8*)(kc);
    bf16x8 kf1 = *(const bf16x8*)(kc + 16 * 512);
    bf16x8 kf2 = *(const bf16x8*)(kc + 32 * 512);
    bf16x8 kf3 = *(const bf16x8*)(kc + 48 * 512);
    bf16x8 vf00 = *(const bf16x8*)(vc);
    bf16x8 vf01 = *(const bf16x8*)(vc + 32);
    bf16x8 vf10 = *(const bf16x8*)(vc + (size_t)16 * Ns);
    bf16x8 vf11 = *(const bf16x8*)(vc + (size_t)16 * Ns + 32);
    f32x4 s[4][2];
    s[0][0] = __builtin_amdgcn_mfma_f32_16x16x32_bf16(kf0, qf0, zero, 0, 0, 0);
    s[0][1] = __builtin_amdgcn_mfma_f32_16x16x32_bf16(kf0, qf1, zero, 0, 0, 0);
    s[1][0] = __builtin_amdgcn_mfma_f32_16x16x32_bf16(kf1, qf0, zero, 0, 0, 0);
    s[1][1] = __builtin_amdgcn_mfma_f32_16x16x32_bf16(kf1, qf1, zero, 0, 0, 0);
    s[2][0] = __builtin_amdgcn_mfma_f32_16x16x32_bf16(kf2, qf0, zero, 0, 0, 0);
    s[2][1] = __builtin_amdgcn_mfma_f32_16x16x32_bf16(kf2, qf1, zero, 0, 0, 0);
    s[3][0] = __builtin_amdgcn_mfma_f32_16x16x32_bf16(kf3, qf0, zero, 0, 0, 0);
    s[3][1] = __builtin_amdgcn_mfma_f32_16x16x32_bf16(kf3, qf1, zero, 0, 0, 0);
    #pragma unroll
    for (int mt = 0; mt < 4; ++mt) {
      #pragma unroll
      for (int nt = 0; nt < 2; ++nt) {
        float e0 = EXP2(s[mt][nt].x);
        float e1 = EXP2(s[mt][nt].y);
        float e2 = EXP2(s[mt][nt].z);
        float e3 = EXP2(s[mt][nt].w);
        if (nt == 0) lsum0 += (e0 + e1) + (e2 + e3);
        else         lsum1 += (e0 + e1) + (e2 + e3);
        uint2 pk;                                   // bf16-truncate pack, 1 op/pair
        pk.x = __builtin_amdgcn_perm(__float_as_uint(e1), __float_as_uint(e0), 0x07060302);
        pk.y = __builtin_amdgcn_perm(__float_as_uint(e3), __float_as_uint(e2), 0x07060302);
        *(uint2*)&ptw[(nt * 16 + ln) * 72 + mt * 16 + quad * 4] = pk;
      }
    }
    #pragma unroll
    for (int ks = 0; ks < 2; ++ks) {
      bf16x8 pf0 = *(const bf16x8*)&ptw[ln * 72 + ks * 32 + quad * 8];
      bf16x8 pf1 = *(const bf16x8*)&ptw[(16 + ln) * 72 + ks * 32 + quad * 8];
      bf16x8 va = ks ? vf01 : vf00;
      bf16x8 vbf = ks ? vf11 : vf10;
      acc[0][0] = __builtin_amdgcn_mfma_f32_16x16x32_bf16(va, pf0, acc[0][0], 0, 0, 0);
      acc[0][1] = __builtin_amdgcn_mfma_f32_16x16x32_bf16(va, pf1, acc[0][1], 0, 0, 0);
      acc[1][0] = __builtin_amdgcn_mfma_f32_16x16x32_bf16(vbf, pf0, acc[1][0], 0, 0, 0);
      acc[1][1] = __builtin_amdgcn_mfma_f32_16x16x32_bf16(vbf, pf1, acc[1][1], 0, 0, 0);
    }
  }
  lsum0 += __shfl_xor(lsum0, 16, 64);
  lsum0 += __shfl_xor(lsum0, 32, 64);
  lsum1 += __shfl_xor(lsum1, 16, 64);
  lsum1 += __shfl_xor(lsum1, 32, 64);
  float* ap = accp + ((size_t)sp * 256 + h * 32) * Ns;
  #pragma unroll
  for (int dt = 0; dt < 2; ++dt) {
    #pragma unroll
    for (int r = 0; r < 4; ++r) {
      int cl = dt * 16 + quad * 4 + r;
      ap[(size_t)cl * Ns + n0 + ln]      = ((const float*)&acc[dt][0])[r];
      ap[(size_t)cl * Ns + n0 + 16 + ln] = ((const float*)&acc[dt][1])[r];
    }
  }
  if (lane < 16) {
    float* lp = lsump + ((size_t)sp * 8 + h) * Ns + n0;
    lp[lane]      = lsum0;
    lp[16 + lane] = lsum1;
  }
}

// ---------------- combine kv-split partials: out = sum(acc) / sum(lsum) ---------
__global__ __launch_bounds__(256) void combine_kernel(const float* __restrict__ accp,
    const float* __restrict__ lsump, float* __restrict__ out, int lgNs) {
  int id = blockIdx.x * 256 + threadIdx.x;
  int Ns = 1 << lgNs;
  int n = id & (Ns - 1);
  int h = id >> (lgNs + 5);
  int sA = 256 << lgNs;
  int sL = 8 << lgNs;
  float v = accp[id] + accp[id + sA] + accp[id + 2 * sA] + accp[id + 3 * sA];
  int li = (h << lgNs) + n;
  float d = lsump[li] + lsump[li + sL] + lsump[li + 2 * sL] + lsump[li + 3 * sL];
  out[id] = v / d;
}

// ---------------- bilinear upsample to 64x64 (jax half-pixel + edge clamp) -------
__global__ __launch_bounds__(256) void upsample_kernel(const float* __restrict__ src,
                                                       float* __restrict__ dst, int lgHs) {
  int Hs = 1 << lgHs;
  int id = blockIdx.x * 256 + threadIdx.x;
  int c = id >> 12, n = id & 4095;
  int y = n >> 6, x = n & 63;
  float sc = (float)Hs / 64.0f;
  float fy = ((float)y + 0.5f) * sc - 0.5f;
  float fx = ((float)x + 0.5f) * sc - 0.5f;
  float fy0 = floorf(fy), fx0 = floorf(fx);
  int y0 = (int)fy0, x0 = (int)fx0;
  float ty = fy - fy0, tx = fx - fx0;
  int y0c = min(max(y0, 0), Hs - 1), y1c = min(max(y0 + 1, 0), Hs - 1);
  int x0c = min(max(x0, 0), Hs - 1), x1c = min(max(x0 + 1, 0), Hs - 1);
  const float* s = src + c * Hs * Hs;
  float v00 = s[y0c * Hs + x0c], v01 = s[y0c * Hs + x1c];
  float v10 = s[y1c * Hs + x0c], v11 = s[y1c * Hs + x1c];
  float v0 = v00 + (v01 - v00) * tx;
  float v1 = v10 + (v11 - v10) * tx;
  dst[id] = v0 + (v1 - v0) * ty;
}

// ---------------- fusion GEMM via bf16 MFMA, split-K=3 --------------------------
// Wf bf16 [256][768], catT bf16 [4096][768]; part[sp][256][4096] fp32.
__global__ __launch_bounds__(256) void gemm_fus_mfma(const unsigned short* __restrict__ Wf,
    const unsigned short* __restrict__ catT, float* __restrict__ part) {
  const int t = threadIdx.x;
  const int wave = t >> 6, lane = t & 63;
  const int ln = lane & 15, quad = lane >> 4;
  const int o0 = blockIdx.x * 64 + (wave & 1) * 32;
  const int n0 = blockIdx.y * 64 + (wave >> 1) * 32;
  const int sp = blockIdx.z;
  const int k0 = sp * 256;
  const unsigned short* a0 = Wf + (size_t)(o0 + ln) * 768 + k0 + quad * 8;
  const unsigned short* a1 = a0 + 16 * 768;
  const unsigned short* b0 = catT + (size_t)(n0 + ln) * 768 + k0 + quad * 8;
  const unsigned short* b1 = b0 + 16 * 768;
  f32x4 acc[2][2] = {};
  #pragma unroll
  for (int ks = 0; ks < 8; ++ks) {
    bf16x8 af0 = *(const bf16x8*)(a0 + ks * 32);
    bf16x8 af1 = *(const bf16x8*)(a1 + ks * 32);
    bf16x8 bv0 = *(const bf16x8*)(b0 + ks * 32);
    bf16x8 bv1 = *(const bf16x8*)(b1 + ks * 32);
    acc[0][0] = __builtin_amdgcn_mfma_f32_16x16x32_bf16(af0, bv0, acc[0][0], 0, 0, 0);
    acc[0][1] = __builtin_amdgcn_mfma_f32_16x16x32_bf16(af0, bv1, acc[0][1], 0, 0, 0);
    acc[1][0] = __builtin_amdgcn_mfma_f32_16x16x32_bf16(af1, bv0, acc[1][0], 0, 0, 0);
    acc[1][1] = __builtin_amdgcn_mfma_f32_16x16x32_bf16(af1, bv1, acc[1][1], 0, 0, 0);
  }
  float* pp = part + (size_t)sp * 1048576;
  #pragma unroll
  for (int mt = 0; mt < 2; ++mt) {
    #pragma unroll
    for (int nt = 0; nt < 2; ++nt) {
      #pragma unroll
      for (int r = 0; r < 4; ++r) {
        pp[(size_t)(o0 + mt * 16 + quad * 4 + r) * 4096 + n0 + nt * 16 + ln] =
            ((const float*)&acc[mt][nt])[r];
      }
    }
  }
}

// ---------------- fusion combine: out = p0+p1+p2 + bias -------------------------
__global__ __launch_bounds__(256) void fus_combine_kernel(const float* __restrict__ part,
    const float* __restrict__ bias, float* __restrict__ out) {
  int id = blockIdx.x * 256 + threadIdx.x;          // float4 index
  int o = id >> 10;                                 // 4096/4 groups per o-row
  float4 v0 = *(const float4*)(part + id * 4);
  float4 v1 = *(const float4*)(part + 1048576 + id * 4);
  float4 v2 = *(const float4*)(part + 2097152 + id * 4);
  float bs = bias[o];
  float4 r;
  r.x = v0.x + v1.x + v2.x + bs;
  r.y = v0.y + v1.y + v2.y + bs;
  r.z = v0.z + v1.z + v2.z + bs;
  r.w = v0.w + v1.w + v2.w + bs;
  *(float4*)(out + id * 4) = r;
}

extern "C" void kernel_launch(void* const* d_in, const int* in_sizes, int n_in,
                              void* d_out, int out_size, void* d_ws, size_t ws_size,
                              hipStream_t stream) {
  const float* x     = (const float*)d_in[0];
  const float* dw_w  = (const float*)d_in[1];
  const float* dw_b  = (const float*)d_in[2];
  const float* pw_w  = (const float*)d_in[3];
  const float* pw_b  = (const float*)d_in[4];
  const float* pos_w = (const float*)d_in[5];
  const float* pos_b = (const float*)d_in[6];
  const float* fus_w = (const float*)d_in[7];
  const float* fus_b = (const float*)d_in[8];
  float* out = (float*)d_out;
  float* ws = (float*)d_ws;

  // ws layout (floats), total 11,665,408 (46.66 MB)
  float* xs2   = ws;                         // 262,144
  float* xs4   = ws + 262144;                // 65,536
  float* xdw   = ws + 327680;                // 1,048,576 (also attn partials s2/s4)
  float* posb  = ws + 1376256;               // 1,048,576
  float* accp  = ws + 2424832;               // 4,194,304 (also cat fp32, fusion part)
  float* lsump = ws + 6619136;               // 131,072
  float* out2  = ws + 6750208;               // 262,144
  float* out4  = ws + 7012352;               // 65,536
  unsigned short* xdwT = (unsigned short*)(ws + 7077888);   // 1,048,576 us
  unsigned short* posT = (unsigned short*)(ws + 7602176);   // 1,048,576 us
  unsigned short* qkvT = (unsigned short*)(ws + 8126464);   // 2,097,152 us
  unsigned short* Vb   = (unsigned short*)(ws + 9175040);   // 1,048,576 us
  unsigned short* catT = (unsigned short*)(ws + 9699328);   // 3,145,728 us
  unsigned short* Wb   = (unsigned short*)(ws + 11272192);  //   589,824 us
  unsigned short* Wf   = (unsigned short*)(ws + 11567104);  //   196,608 us
  float* cat  = accp;                        // fp32 cat aliases accp (safe: see combine)
  float* part = accp;                        // fusion partials alias accp (cat dead then)

  avgpool_kernel<<<1024, 256, 0, stream>>>(x, xs2, 1);
  avgpool_kernel<<<256, 256, 0, stream>>>(x, xs4, 2);
  cvt_kernel<<<576, 256, 0, stream>>>(pw_w, Wb);     // all 3 scales at once
  cvt_kernel<<<192, 256, 0, stream>>>(fus_w, Wf);

  // ---- scale 1 (Hs=64, Ns=4096) -> cat rows 0..255 ----
  dwconv_kernel<<<4096, 256, 0, stream>>>(x, dw_w, dw_b, pos_w, pos_b, xdw, posb, 6);
  transpose_cvt_kernel<<<dim3(64, 4), 256, 0, stream>>>(xdw, xdwT, 256, 4096);
  transpose_cvt_kernel<<<dim3(64, 4), 256, 0, stream>>>(posb, posT, 256, 4096);
  gemm_qkv_mfma<<<dim3(12, 64), 256, 0, stream>>>(Wb, xdwT, pw_b, posT, qkvT, Vb, 4096);
  attn2_kernel<<<dim3(32, 8, 4), 256, 0, stream>>>(qkvT, Vb, accp, lsump, 4096, 10);
  combine_kernel<<<4096, 256, 0, stream>>>(accp, lsump, cat, 12);  // aliases accp sp0: per-thread read-before-write

  // ---- scale 2 (Hs=32, Ns=1024); attn partials -> xdw buffer ----
  dwconv_kernel<<<1024, 256, 0, stream>>>(xs2, dw_w + 2304, dw_b + 256, pos_w + 2304,
                                          pos_b + 256, xdw, posb, 5);
  transpose_cvt_kernel<<<dim3(16, 4), 256, 0, stream>>>(xdw, xdwT, 256, 1024);
  transpose_cvt_kernel<<<dim3(16, 4), 256, 0, stream>>>(posb, posT, 256, 1024);
  gemm_qkv_mfma<<<dim3(12, 16), 256, 0, stream>>>(Wb + 196608, xdwT, pw_b + 768, posT,
                                                  qkvT, Vb, 1024);
  attn2_kernel<<<dim3(8, 8, 4), 256, 0, stream>>>(qkvT, Vb, xdw, lsump, 1024, 8);
  combine_kernel<<<1024, 256, 0, stream>>>(xdw, lsump, out2, 10);

  // ---- scale 4 (Hs=16, Ns=256); attn partials -> xdw buffer ----
  dwconv_kernel<<<256, 256, 0, stream>>>(xs4, dw_w + 4608, dw_b + 512, pos_w + 4608,
                                         pos_b + 512, xdw, posb, 4);
  transpose_cvt_kernel<<<dim3(4, 4), 256, 0, stream>>>(xdw, xdwT, 256, 256);
  transpose_cvt_kernel<<<dim3(4, 4), 256, 0, stream>>>(posb, posT, 256, 256);
  gemm_qkv_mfma<<<dim3(12, 4), 256, 0, stream>>>(Wb + 393216, xdwT, pw_b + 1536, posT,
                                                 qkvT, Vb, 256);
  attn2_kernel<<<dim3(2, 8, 4), 256, 0, stream>>>(qkvT, Vb, xdw, lsump, 256, 6);
  combine_kernel<<<256, 256, 0, stream>>>(xdw, lsump, out4, 8);

  // ---- upsample into cat rows 256..767 (fp32, within accp region) ----
  upsample_kernel<<<4096, 256, 0, stream>>>(out2, cat + 256 * 4096, 5);
  upsample_kernel<<<4096, 256, 0, stream>>>(out4, cat + 512 * 4096, 4);

  // ---- cat -> catT bf16, then fusion GEMM (split-K=3) + combine ----
  transpose_cvt_kernel<<<dim3(64, 12), 256, 0, stream>>>(cat, catT, 768, 4096);
  gemm_fus_mfma<<<dim3(4, 64, 3), 256, 0, stream>>>(Wf, catT, part);  // part aliases cat (dead)
  fus_combine_kernel<<<1024, 256, 0, stream>>>(part, fus_b, out);
}

// Round 5
// 238.388 us; speedup vs baseline: 2.9104x; 1.0437x over previous
//
#include <hip/hip_runtime.h>
#include <math.h>

#define DIM 256
#define HEADS 8
#define HD 32
// log2(e)/sqrt(32): folded into stored Q so attention uses native exp2
#define QSCALE 0.25504526770295183f

typedef __attribute__((ext_vector_type(8))) short bf16x8;
typedef __attribute__((ext_vector_type(4))) float f32x4;

#if __has_builtin(__builtin_amdgcn_exp2f)
#define EXP2(x) __builtin_amdgcn_exp2f(x)
#else
#define EXP2(x) __expf((x) * 0.6931471805599453f)
#endif

__device__ __forceinline__ unsigned short f2bf(float f) {
  unsigned int u = __float_as_uint(f);
  unsigned int r = u + 0x7fff + ((u >> 16) & 1);   // round-to-nearest-even
  return (unsigned short)(r >> 16);
}
__device__ __forceinline__ float bf2f(unsigned short u) {
  return __uint_as_float(((unsigned int)u) << 16);
}

// ---------------- avg pool (from 256x64x64) ----------------
__global__ __launch_bounds__(256) void avgpool_kernel(const float* __restrict__ x,
                                                      float* __restrict__ out, int lgS) {
  int s = 1 << lgS;
  int lgHs = 6 - lgS;
  int Hs = 1 << lgHs;
  int id = blockIdx.x * 256 + threadIdx.x;
  int c = id >> (2 * lgHs);
  int n = id & ((1 << (2 * lgHs)) - 1);
  int y = (n >> lgHs) << lgS;
  int x0 = (n & (Hs - 1)) << lgS;
  const float* base = x + c * 4096 + y * 64 + x0;
  float sum = 0.f;
  for (int dy = 0; dy < s; ++dy)
    for (int dx = 0; dx < s; ++dx)
      sum += base[dy * 64 + dx];
  out[id] = sum / (float)(s * s);
}

// ---------------- fused depthwise 3x3 (dw + pos), SAME zero pad ----------------
__global__ __launch_bounds__(256) void dwconv_kernel(const float* __restrict__ xs,
    const float* __restrict__ dw_w, const float* __restrict__ dw_b,
    const float* __restrict__ pos_w, const float* __restrict__ pos_b,
    float* __restrict__ xdw, float* __restrict__ pos, int lgHs) {
  int Hs = 1 << lgHs;
  int Ns = Hs * Hs;
  int id = blockIdx.x * 256 + threadIdx.x;
  int c = id >> (2 * lgHs);
  int n = id & (Ns - 1);
  int y = n >> lgHs, x = n & (Hs - 1);
  const float* w1 = dw_w + c * 9;
  const float* w2 = pos_w + c * 9;
  const float* src = xs + c * Ns;
  float s1 = dw_b[c], s2 = pos_b[c];
  #pragma unroll
  for (int ky = 0; ky < 3; ++ky) {
    int yy = y + ky - 1;
    bool yok = (yy >= 0) && (yy < Hs);
    #pragma unroll
    for (int kx = 0; kx < 3; ++kx) {
      int xx = x + kx - 1;
      bool ok = yok && (xx >= 0) && (xx < Hs);
      float v = ok ? src[yy * Hs + xx] : 0.f;
      s1 += v * w1[ky * 3 + kx];
      s2 += v * w2[ky * 3 + kx];
    }
  }
  xdw[id] = s1;
  pos[id] = s2;
}

// ---------------- plain fp32 -> bf16 cvt (weights) ----------------
__global__ __launch_bounds__(256) void cvt_kernel(const float* __restrict__ src,
                                                  unsigned short* __restrict__ dst) {
  int id = blockIdx.x * 256 + threadIdx.x;          // one float4 per thread
  float4 v = *(const float4*)(src + id * 4);
  ushort4 st;
  st.x = f2bf(v.x); st.y = f2bf(v.y); st.z = f2bf(v.z); st.w = f2bf(v.w);
  *(ushort4*)(dst + id * 4) = st;
}

// ---------------- dual transpose + cvt: fp32 [C][N] -> bf16 [N][C], z picks src --
__global__ __launch_bounds__(256) void transpose_dual_kernel(const float* __restrict__ s1,
    const float* __restrict__ s2, unsigned short* __restrict__ d1,
    unsigned short* __restrict__ d2, int C, int N) {
  __shared__ unsigned short lds[64][72];
  const float* src = blockIdx.z ? s2 : s1;
  unsigned short* dst = blockIdx.z ? d2 : d1;
  const int t = threadIdx.x;
  const int n0 = blockIdx.x * 64, c0 = blockIdx.y * 64;
  #pragma unroll
  for (int p = 0; p < 4; ++p) {
    int c = p * 16 + (t >> 4);
    int nn = (t & 15) * 4;
    float4 v = *(const float4*)(src + (size_t)(c0 + c) * N + n0 + nn);
    lds[nn + 0][c] = f2bf(v.x);
    lds[nn + 1][c] = f2bf(v.y);
    lds[nn + 2][c] = f2bf(v.z);
    lds[nn + 3][c] = f2bf(v.w);
  }
  __syncthreads();
  int n = t >> 2, seg = (t & 3) * 16;
  *(bf16x8*)(dst + (size_t)(n0 + n) * C + c0 + seg)     = *(const bf16x8*)&lds[n][seg];
  *(bf16x8*)(dst + (size_t)(n0 + n) * C + c0 + seg + 8) = *(const bf16x8*)&lds[n][seg + 8];
}

// ---------------- QKV GEMM via bf16 MFMA, barrier-free -------------------------
__global__ __launch_bounds__(256) void gemm_qkv_mfma(const unsigned short* __restrict__ Wb,
    const unsigned short* __restrict__ xdwT, const float* __restrict__ bias,
    const unsigned short* __restrict__ posT, unsigned short* __restrict__ qkvT,
    unsigned short* __restrict__ Vb, int Ns) {
  const int t = threadIdx.x;
  const int wave = t >> 6, lane = t & 63;
  const int ln = lane & 15, quad = lane >> 4;
  const int o0 = blockIdx.x * 64 + (wave & 1) * 32;
  const int n0 = blockIdx.y * 64 + (wave >> 1) * 32;
  const unsigned short* a0 = Wb + (size_t)(o0 + ln) * 256 + quad * 8;
  const unsigned short* a1 = a0 + 16 * 256;
  const unsigned short* b0 = xdwT + (size_t)(n0 + ln) * 256 + quad * 8;
  const unsigned short* b1 = b0 + 16 * 256;
  f32x4 acc[2][2] = {};
  #pragma unroll
  for (int ks = 0; ks < 8; ++ks) {
    bf16x8 af0 = *(const bf16x8*)(a0 + ks * 32);
    bf16x8 af1 = *(const bf16x8*)(a1 + ks * 32);
    bf16x8 bv0 = *(const bf16x8*)(b0 + ks * 32);
    bf16x8 bv1 = *(const bf16x8*)(b1 + ks * 32);
    acc[0][0] = __builtin_amdgcn_mfma_f32_16x16x32_bf16(af0, bv0, acc[0][0], 0, 0, 0);
    acc[0][1] = __builtin_amdgcn_mfma_f32_16x16x32_bf16(af0, bv1, acc[0][1], 0, 0, 0);
    acc[1][0] = __builtin_amdgcn_mfma_f32_16x16x32_bf16(af1, bv0, acc[1][0], 0, 0, 0);
    acc[1][1] = __builtin_amdgcn_mfma_f32_16x16x32_bf16(af1, bv1, acc[1][1], 0, 0, 0);
  }
  const int cat = blockIdx.x >> 2;                  // 0=q 1=k 2=v
  #pragma unroll
  for (int mt = 0; mt < 2; ++mt) {
    int ot = o0 + mt * 16 + quad * 4;
    float bs0 = bias[ot], bs1 = bias[ot + 1], bs2 = bias[ot + 2], bs3 = bias[ot + 3];
    #pragma unroll
    for (int nt = 0; nt < 2; ++nt) {
      int nn = n0 + nt * 16 + ln;
      f32x4 v = acc[mt][nt];
      v.x += bs0; v.y += bs1; v.z += bs2; v.w += bs3;
      if (cat < 2) {
        ushort4 p4 = *(const ushort4*)(posT + (size_t)nn * 256 + (ot & 255));
        v.x += bf2f(p4.x); v.y += bf2f(p4.y); v.z += bf2f(p4.z); v.w += bf2f(p4.w);
        if (cat == 0) { v.x *= QSCALE; v.y *= QSCALE; v.z *= QSCALE; v.w *= QSCALE; }
        ushort4 st;
        st.x = f2bf(v.x); st.y = f2bf(v.y); st.z = f2bf(v.z); st.w = f2bf(v.w);
        *(ushort4*)(qkvT + (size_t)nn * 512 + ot) = st;
      } else {
        Vb[(size_t)(ot - 512 + 0) * Ns + nn] = f2bf(v.x);
        Vb[(size_t)(ot - 512 + 1) * Ns + nn] = f2bf(v.y);
        Vb[(size_t)(ot - 512 + 2) * Ns + nn] = f2bf(v.z);
        Vb[(size_t)(ot - 512 + 3) * Ns + nn] = f2bf(v.w);
      }
    }
  }
}

// ---------------- attention v3: barrier-free + register prefetch pipeline -------
// qkvT [Ns][512] bf16 (q pre-scaled by QSCALE incl. pos; k +pos), Vb [256][Ns] bf16
// grid (qtiles, heads, 4 kv-splits); block 256 = 4 waves x 32 queries.
__global__ __launch_bounds__(256) void attn2_kernel(const unsigned short* __restrict__ qkvT,
    const unsigned short* __restrict__ Vb, float* __restrict__ accp,
    float* __restrict__ lsump, int Ns, int lgMs) {
  __shared__ unsigned short pt_lds[4 * 32 * 72];    // wave-private P^T [n][m], pad 72
  const int t = threadIdx.x;
  const int wave = t >> 6, lane = t & 63;
  const int ln = lane & 15, quad = lane >> 4;
  const int h = blockIdx.y, sp = blockIdx.z;
  const int n0 = blockIdx.x * 128 + wave * 32;
  const unsigned short* qb = qkvT + (size_t)n0 * 512 + h * 32 + quad * 8;
  bf16x8 qf0 = *(const bf16x8*)(qb + (size_t)ln * 512);
  bf16x8 qf1 = *(const bf16x8*)(qb + (size_t)(16 + ln) * 512);
  unsigned short* ptw = pt_lds + wave * (32 * 72);
  f32x4 acc[2][2] = {};
  float lsum0 = 0.f, lsum1 = 0.f;
  const f32x4 zero = {0.f, 0.f, 0.f, 0.f};
  const int m0s = sp << lgMs;
  const int nch = 1 << (lgMs - 6);
  const unsigned short* kb = qkvT + (size_t)(m0s + ln) * 512 + 256 + h * 32 + quad * 8;
  const unsigned short* vb = Vb + (size_t)(h * 32 + ln) * Ns + m0s + quad * 8;
  // prologue: load chunk 0
  bf16x8 kf0 = *(const bf16x8*)(kb);
  bf16x8 kf1 = *(const bf16x8*)(kb + 16 * 512);
  bf16x8 kf2 = *(const bf16x8*)(kb + 32 * 512);
  bf16x8 kf3 = *(const bf16x8*)(kb + 48 * 512);
  bf16x8 vf00 = *(const bf16x8*)(vb);
  bf16x8 vf01 = *(const bf16x8*)(vb + 32);
  bf16x8 vf10 = *(const bf16x8*)(vb + (size_t)16 * Ns);
  bf16x8 vf11 = *(const bf16x8*)(vb + (size_t)16 * Ns + 32);
  for (int ch = 0; ch < nch; ++ch) {
    // prefetch chunk ch+1 (re-loads last chunk on final iter; harmless)
    int nc = (ch + 1 < nch) ? (ch + 1) : ch;
    const unsigned short* kn = kb + (size_t)nc * 64 * 512;
    const unsigned short* vn = vb + nc * 64;
    bf16x8 nkf0 = *(const bf16x8*)(kn);
    bf16x8 nkf1 = *(const bf16x8*)(kn + 16 * 512);
    bf16x8 nkf2 = *(const bf16x8*)(kn + 32 * 512);
    bf16x8 nkf3 = *(const bf16x8*)(kn + 48 * 512);
    bf16x8 nvf00 = *(const bf16x8*)(vn);
    bf16x8 nvf01 = *(const bf16x8*)(vn + 32);
    bf16x8 nvf10 = *(const bf16x8*)(vn + (size_t)16 * Ns);
    bf16x8 nvf11 = *(const bf16x8*)(vn + (size_t)16 * Ns + 32);
    // compute with current chunk's registers
    f32x4 s[4][2];
    s[0][0] = __builtin_amdgcn_mfma_f32_16x16x32_bf16(kf0, qf0, zero, 0, 0, 0);
    s[0][1] = __builtin_amdgcn_mfma_f32_16x16x32_bf16(kf0, qf1, zero, 0, 0, 0);
    s[1][0] = __builtin_amdgcn_mfma_f32_16x16x32_bf16(kf1, qf0, zero, 0, 0, 0);
    s[1][1] = __builtin_amdgcn_mfma_f32_16x16x32_bf16(kf1, qf1, zero, 0, 0, 0);
    s[2][0] = __builtin_amdgcn_mfma_f32_16x16x32_bf16(kf2, qf0, zero, 0, 0, 0);
    s[2][1] = __builtin_amdgcn_mfma_f32_16x16x32_bf16(kf2, qf1, zero, 0, 0, 0);
    s[3][0] = __builtin_amdgcn_mfma_f32_16x16x32_bf16(kf3, qf0, zero, 0, 0, 0);
    s[3][1] = __builtin_amdgcn_mfma_f32_16x16x32_bf16(kf3, qf1, zero, 0, 0, 0);
    #pragma unroll
    for (int mt = 0; mt < 4; ++mt) {
      #pragma unroll
      for (int nt = 0; nt < 2; ++nt) {
        float e0 = EXP2(s[mt][nt].x);
        float e1 = EXP2(s[mt][nt].y);
        float e2 = EXP2(s[mt][nt].z);
        float e3 = EXP2(s[mt][nt].w);
        if (nt == 0) lsum0 += (e0 + e1) + (e2 + e3);
        else         lsum1 += (e0 + e1) + (e2 + e3);
        uint2 pk;                                   // bf16-truncate pack, 1 op/pair
        pk.x = __builtin_amdgcn_perm(__float_as_uint(e1), __float_as_uint(e0), 0x07060302);
        pk.y = __builtin_amdgcn_perm(__float_as_uint(e3), __float_as_uint(e2), 0x07060302);
        *(uint2*)&ptw[(nt * 16 + ln) * 72 + mt * 16 + quad * 4] = pk;
      }
    }
    #pragma unroll
    for (int ks = 0; ks < 2; ++ks) {
      bf16x8 pf0 = *(const bf16x8*)&ptw[ln * 72 + ks * 32 + quad * 8];
      bf16x8 pf1 = *(const bf16x8*)&ptw[(16 + ln) * 72 + ks * 32 + quad * 8];
      bf16x8 va = ks ? vf01 : vf00;
      bf16x8 vbf = ks ? vf11 : vf10;
      acc[0][0] = __builtin_amdgcn_mfma_f32_16x16x32_bf16(va, pf0, acc[0][0], 0, 0, 0);
      acc[0][1] = __builtin_amdgcn_mfma_f32_16x16x32_bf16(va, pf1, acc[0][1], 0, 0, 0);
      acc[1][0] = __builtin_amdgcn_mfma_f32_16x16x32_bf16(vbf, pf0, acc[1][0], 0, 0, 0);
      acc[1][1] = __builtin_amdgcn_mfma_f32_16x16x32_bf16(vbf, pf1, acc[1][1], 0, 0, 0);
    }
    kf0 = nkf0; kf1 = nkf1; kf2 = nkf2; kf3 = nkf3;
    vf00 = nvf00; vf01 = nvf01; vf10 = nvf10; vf11 = nvf11;
  }
  lsum0 += __shfl_xor(lsum0, 16, 64);
  lsum0 += __shfl_xor(lsum0, 32, 64);
  lsum1 += __shfl_xor(lsum1, 16, 64);
  lsum1 += __shfl_xor(lsum1, 32, 64);
  float* ap = accp + ((size_t)sp * 256 + h * 32) * Ns;
  #pragma unroll
  for (int dt = 0; dt < 2; ++dt) {
    #pragma unroll
    for (int r = 0; r < 4; ++r) {
      int cl = dt * 16 + quad * 4 + r;
      ap[(size_t)cl * Ns + n0 + ln]      = ((const float*)&acc[dt][0])[r];
      ap[(size_t)cl * Ns + n0 + 16 + ln] = ((const float*)&acc[dt][1])[r];
    }
  }
  if (lane < 16) {
    float* lp = lsump + ((size_t)sp * 8 + h) * Ns + n0;
    lp[lane]      = lsum0;
    lp[16 + lane] = lsum1;
  }
}

// ---------------- combine kv-split partials: out = sum(acc) / sum(lsum) ---------
__global__ __launch_bounds__(256) void combine_kernel(const float* __restrict__ accp,
    const float* __restrict__ lsump, float* __restrict__ out, int lgNs) {
  int id = blockIdx.x * 256 + threadIdx.x;
  int Ns = 1 << lgNs;
  int n = id & (Ns - 1);
  int h = id >> (lgNs + 5);
  int sA = 256 << lgNs;
  int sL = 8 << lgNs;
  float v = accp[id] + accp[id + sA] + accp[id + 2 * sA] + accp[id + 3 * sA];
  int li = (h << lgNs) + n;
  float d = lsump[li] + lsump[li + sL] + lsump[li + 2 * sL] + lsump[li + 3 * sL];
  out[id] = v / d;
}

// ---------------- build catT bf16 [4096][768] directly --------------------------
// by 0..3:  c 0..255   = attn-s1 combine (accp 4 splits / lsum1)
// by 4..7:  c 256..511 = bilinear upsample of out2 (32x32)
// by 8..11: c 512..767 = bilinear upsample of out4 (16x16)
__global__ __launch_bounds__(256) void build_catT_kernel(const float* __restrict__ accp,
    const float* __restrict__ lsum1, const float* __restrict__ out2,
    const float* __restrict__ out4, unsigned short* __restrict__ catT) {
  __shared__ unsigned short lds[64][72];
  const int t = threadIdx.x;
  const int n0 = blockIdx.x * 64;
  const int by = blockIdx.y;
  const int c0 = by * 64;
  if (by < 4) {
    #pragma unroll
    for (int p = 0; p < 4; ++p) {
      int ct = p * 16 + (t >> 4);
      int c = c0 + ct;
      int h = c >> 5;
      int nn = (t & 15) * 4;
      size_t base = (size_t)c * 4096 + n0 + nn;
      float4 a0 = *(const float4*)(accp + base);
      float4 a1 = *(const float4*)(accp + base + (size_t)256 * 4096);
      float4 a2 = *(const float4*)(accp + base + (size_t)512 * 4096);
      float4 a3 = *(const float4*)(accp + base + (size_t)768 * 4096);
      size_t lb = (size_t)h * 4096 + n0 + nn;
      float4 d0 = *(const float4*)(lsum1 + lb);
      float4 d1 = *(const float4*)(lsum1 + lb + 8 * 4096);
      float4 d2 = *(const float4*)(lsum1 + lb + 16 * 4096);
      float4 d3 = *(const float4*)(lsum1 + lb + 24 * 4096);
      lds[nn + 0][ct] = f2bf((a0.x + a1.x + a2.x + a3.x) / (d0.x + d1.x + d2.x + d3.x));
      lds[nn + 1][ct] = f2bf((a0.y + a1.y + a2.y + a3.y) / (d0.y + d1.y + d2.y + d3.y));
      lds[nn + 2][ct] = f2bf((a0.z + a1.z + a2.z + a3.z) / (d0.z + d1.z + d2.z + d3.z));
      lds[nn + 3][ct] = f2bf((a0.w + a1.w + a2.w + a3.w) / (d0.w + d1.w + d2.w + d3.w));
    }
  } else {
    const bool s2 = by < 8;
    const float* src = s2 ? out2 : out4;
    const int Hs = s2 ? 32 : 16;
    const int coff = s2 ? 256 : 512;
    const float sc = (float)Hs / 64.0f;
    #pragma unroll
    for (int p = 0; p < 4; ++p) {
      int ct = p * 16 + (t >> 4);
      const float* s = src + (size_t)(c0 - coff + ct) * Hs * Hs;
      int nn = (t & 15) * 4;
      #pragma unroll
      for (int i = 0; i < 4; ++i) {
        int n = n0 + nn + i;
        int y = n >> 6, x = n & 63;
        float fy = ((float)y + 0.5f) * sc - 0.5f;
        float fx = ((float)x + 0.5f) * sc - 0.5f;
        float fy0 = floorf(fy), fx0 = floorf(fx);
        int y0 = (int)fy0, x0 = (int)fx0;
        float ty = fy - fy0, tx = fx - fx0;
        int y0c = min(max(y0, 0), Hs - 1), y1c = min(max(y0 + 1, 0), Hs - 1);
        int x0c = min(max(x0, 0), Hs - 1), x1c = min(max(x0 + 1, 0), Hs - 1);
        float v00 = s[y0c * Hs + x0c], v01 = s[y0c * Hs + x1c];
        float v10 = s[y1c * Hs + x0c], v11 = s[y1c * Hs + x1c];
        float v0 = v00 + (v01 - v00) * tx;
        float v1 = v10 + (v11 - v10) * tx;
        lds[nn + i][ct] = f2bf(v0 + (v1 - v0) * ty);
      }
    }
  }
  __syncthreads();
  int n = t >> 2, seg = (t & 3) * 16;
  *(bf16x8*)(catT + (size_t)(n0 + n) * 768 + c0 + seg)     = *(const bf16x8*)&lds[n][seg];
  *(bf16x8*)(catT + (size_t)(n0 + n) * 768 + c0 + seg + 8) = *(const bf16x8*)&lds[n][seg + 8];
}

// ---------------- fusion GEMM via bf16 MFMA, split-K=3 --------------------------
__global__ __launch_bounds__(256) void gemm_fus_mfma(const unsigned short* __restrict__ Wf,
    const unsigned short* __restrict__ catT, float* __restrict__ part) {
  const int t = threadIdx.x;
  const int wave = t >> 6, lane = t & 63;
  const int ln = lane & 15, quad = lane >> 4;
  const int o0 = blockIdx.x * 64 + (wave & 1) * 32;
  const int n0 = blockIdx.y * 64 + (wave >> 1) * 32;
  const int sp = blockIdx.z;
  const int k0 = sp * 256;
  const unsigned short* a0 = Wf + (size_t)(o0 + ln) * 768 + k0 + quad * 8;
  const unsigned short* a1 = a0 + 16 * 768;
  const unsigned short* b0 = catT + (size_t)(n0 + ln) * 768 + k0 + quad * 8;
  const unsigned short* b1 = b0 + 16 * 768;
  f32x4 acc[2][2] = {};
  #pragma unroll
  for (int ks = 0; ks < 8; ++ks) {
    bf16x8 af0 = *(const bf16x8*)(a0 + ks * 32);
    bf16x8 af1 = *(const bf16x8*)(a1 + ks * 32);
    bf16x8 bv0 = *(const bf16x8*)(b0 + ks * 32);
    bf16x8 bv1 = *(const bf16x8*)(b1 + ks * 32);
    acc[0][0] = __builtin_amdgcn_mfma_f32_16x16x32_bf16(af0, bv0, acc[0][0], 0, 0, 0);
    acc[0][1] = __builtin_amdgcn_mfma_f32_16x16x32_bf16(af0, bv1, acc[0][1], 0, 0, 0);
    acc[1][0] = __builtin_amdgcn_mfma_f32_16x16x32_bf16(af1, bv0, acc[1][0], 0, 0, 0);
    acc[1][1] = __builtin_amdgcn_mfma_f32_16x16x32_bf16(af1, bv1, acc[1][1], 0, 0, 0);
  }
  float* pp = part + (size_t)sp * 1048576;
  #pragma unroll
  for (int mt = 0; mt < 2; ++mt) {
    #pragma unroll
    for (int nt = 0; nt < 2; ++nt) {
      #pragma unroll
      for (int r = 0; r < 4; ++r) {
        pp[(size_t)(o0 + mt * 16 + quad * 4 + r) * 4096 + n0 + nt * 16 + ln] =
            ((const float*)&acc[mt][nt])[r];
      }
    }
  }
}

// ---------------- fusion combine: out = p0+p1+p2 + bias -------------------------
__global__ __launch_bounds__(256) void fus_combine_kernel(const float* __restrict__ part,
    const float* __restrict__ bias, float* __restrict__ out) {
  int id = blockIdx.x * 256 + threadIdx.x;          // float4 index
  int o = id >> 10;
  float4 v0 = *(const float4*)(part + id * 4);
  float4 v1 = *(const float4*)(part + 1048576 + id * 4);
  float4 v2 = *(const float4*)(part + 2097152 + id * 4);
  float bs = bias[o];
  float4 r;
  r.x = v0.x + v1.x + v2.x + bs;
  r.y = v0.y + v1.y + v2.y + bs;
  r.z = v0.z + v1.z + v2.z + bs;
  r.w = v0.w + v1.w + v2.w + bs;
  *(float4*)(out + id * 4) = r;
}

extern "C" void kernel_launch(void* const* d_in, const int* in_sizes, int n_in,
                              void* d_out, int out_size, void* d_ws, size_t ws_size,
                              hipStream_t stream) {
  const float* x     = (const float*)d_in[0];
  const float* dw_w  = (const float*)d_in[1];
  const float* dw_b  = (const float*)d_in[2];
  const float* pw_w  = (const float*)d_in[3];
  const float* pw_b  = (const float*)d_in[4];
  const float* pos_w = (const float*)d_in[5];
  const float* pos_b = (const float*)d_in[6];
  const float* fus_w = (const float*)d_in[7];
  const float* fus_b = (const float*)d_in[8];
  float* out = (float*)d_out;
  float* ws = (float*)d_ws;

  // ws layout (floats), total 11,706,368 (~46.8 MB)
  float* xs2    = ws;                        // 262,144
  float* xs4    = ws + 262144;               // 65,536
  float* xdw    = ws + 327680;               // 1,048,576 (dwconv out; attn partials s2/s4)
  float* posb   = ws + 1376256;              // 1,048,576
  float* accp   = ws + 2424832;              // 4,194,304 (s1 partials; later fusion part)
  float* lsump1 = ws + 6619136;              // 131,072
  float* lsump2 = ws + 6750208;              // 32,768
  float* lsump4 = ws + 6782976;              // 8,192
  float* out2   = ws + 6791168;              // 262,144
  float* out4   = ws + 7053312;              // 65,536
  unsigned short* xdwT = (unsigned short*)(ws + 7118848);   // 1,048,576 us
  unsigned short* posT = (unsigned short*)(ws + 7643136);   // 1,048,576 us
  unsigned short* qkvT = (unsigned short*)(ws + 8167424);   // 2,097,152 us
  unsigned short* Vb   = (unsigned short*)(ws + 9216000);   // 1,048,576 us
  unsigned short* catT = (unsigned short*)(ws + 9740288);   // 3,145,728 us
  unsigned short* Wb   = (unsigned short*)(ws + 11313152);  //   589,824 us
  unsigned short* Wf   = (unsigned short*)(ws + 11608064);  //   196,608 us
  float* part = accp;                        // fusion partials alias accp (dead then)

  avgpool_kernel<<<1024, 256, 0, stream>>>(x, xs2, 1);
  avgpool_kernel<<<256, 256, 0, stream>>>(x, xs4, 2);
  cvt_kernel<<<576, 256, 0, stream>>>(pw_w, Wb);
  cvt_kernel<<<192, 256, 0, stream>>>(fus_w, Wf);

  // ---- scale 1 (Hs=64, Ns=4096): partials stay in accp until build_catT ----
  dwconv_kernel<<<4096, 256, 0, stream>>>(x, dw_w, dw_b, pos_w, pos_b, xdw, posb, 6);
  transpose_dual_kernel<<<dim3(64, 4, 2), 256, 0, stream>>>(xdw, posb, xdwT, posT, 256, 4096);
  gemm_qkv_mfma<<<dim3(12, 64), 256, 0, stream>>>(Wb, xdwT, pw_b, posT, qkvT, Vb, 4096);
  attn2_kernel<<<dim3(32, 8, 4), 256, 0, stream>>>(qkvT, Vb, accp, lsump1, 4096, 10);

  // ---- scale 2 (Hs=32, Ns=1024); attn partials -> xdw ----
  dwconv_kernel<<<1024, 256, 0, stream>>>(xs2, dw_w + 2304, dw_b + 256, pos_w + 2304,
                                          pos_b + 256, xdw, posb, 5);
  transpose_dual_kernel<<<dim3(16, 4, 2), 256, 0, stream>>>(xdw, posb, xdwT, posT, 256, 1024);
  gemm_qkv_mfma<<<dim3(12, 16), 256, 0, stream>>>(Wb + 196608, xdwT, pw_b + 768, posT,
                                                  qkvT, Vb, 1024);
  attn2_kernel<<<dim3(8, 8, 4), 256, 0, stream>>>(qkvT, Vb, xdw, lsump2, 1024, 8);
  combine_kernel<<<1024, 256, 0, stream>>>(xdw, lsump2, out2, 10);

  // ---- scale 4 (Hs=16, Ns=256); attn partials -> xdw ----
  dwconv_kernel<<<256, 256, 0, stream>>>(xs4, dw_w + 4608, dw_b + 512, pos_w + 4608,
                                         pos_b + 512, xdw, posb, 4);
  transpose_dual_kernel<<<dim3(4, 4, 2), 256, 0, stream>>>(xdw, posb, xdwT, posT, 256, 256);
  gemm_qkv_mfma<<<dim3(12, 4), 256, 0, stream>>>(Wb + 393216, xdwT, pw_b + 1536, posT,
                                                 qkvT, Vb, 256);
  attn2_kernel<<<dim3(2, 8, 4), 256, 0, stream>>>(qkvT, Vb, xdw, lsump4, 256, 6);
  combine_kernel<<<256, 256, 0, stream>>>(xdw, lsump4, out4, 8);

  // ---- build catT bf16 (combine-s1 + upsample fused), then fusion ----
  build_catT_kernel<<<dim3(64, 12), 256, 0, stream>>>(accp, lsump1, out2, out4, catT);
  gemm_fus_mfma<<<dim3(4, 64, 3), 256, 0, stream>>>(Wf, catT, part);
  fus_combine_kernel<<<1024, 256, 0, stream>>>(part, fus_b, out);
}

// Round 6
// 205.961 us; speedup vs baseline: 3.3686x; 1.1574x over previous
//
#include <hip/hip_runtime.h>
#include <math.h>

#define DIM 256
#define HEADS 8
#define HD 32
// log2(e)/sqrt(32): folded into stored Q so attention uses native exp2
#define QSCALE 0.25504526770295183f

typedef __attribute__((ext_vector_type(8))) short bf16x8;
typedef __attribute__((ext_vector_type(4))) float f32x4;

#if __has_builtin(__builtin_amdgcn_exp2f)
#define EXP2(x) __builtin_amdgcn_exp2f(x)
#else
#define EXP2(x) __expf((x) * 0.6931471805599453f)
#endif

__device__ __forceinline__ unsigned short f2bf(float f) {
  unsigned int u = __float_as_uint(f);
  unsigned int r = u + 0x7fff + ((u >> 16) & 1);   // round-to-nearest-even
  return (unsigned short)(r >> 16);
}
__device__ __forceinline__ float bf2f(unsigned short u) {
  return __uint_as_float(((unsigned int)u) << 16);
}

// ---------------- prep: both avgpools + both weight cvts in one launch ----------
__global__ __launch_bounds__(256) void prep_kernel(const float* __restrict__ x,
    const float* __restrict__ pw_w, const float* __restrict__ fus_w,
    float* __restrict__ xs2, float* __restrict__ xs4,
    unsigned short* __restrict__ Wb, unsigned short* __restrict__ Wf) {
  const int gx = blockIdx.x, t = threadIdx.x;
  if (gx < 1024) {                                  // avgpool s=2 -> 256x32x32
    int id = gx * 256 + t;
    int c = id >> 10, n = id & 1023;
    int y = (n >> 5) << 1, x0 = (n & 31) << 1;
    const float* b = x + c * 4096 + y * 64 + x0;
    xs2[id] = (b[0] + b[1] + b[64] + b[65]) * 0.25f;
  } else if (gx < 1280) {                           // avgpool s=4 -> 256x16x16
    int id = (gx - 1024) * 256 + t;
    int c = id >> 8, n = id & 255;
    int y = (n >> 4) << 2, x0 = (n & 15) << 2;
    const float* b = x + c * 4096 + y * 64 + x0;
    float s = 0.f;
    #pragma unroll
    for (int dy = 0; dy < 4; ++dy)
      #pragma unroll
      for (int dx = 0; dx < 4; ++dx) s += b[dy * 64 + dx];
    xs4[id] = s * 0.0625f;
  } else if (gx < 1856) {                           // cvt pw_w -> Wb (589824 fl)
    int id = (gx - 1280) * 256 + t;
    float4 v = *(const float4*)(pw_w + id * 4);
    ushort4 st; st.x = f2bf(v.x); st.y = f2bf(v.y); st.z = f2bf(v.z); st.w = f2bf(v.w);
    *(ushort4*)(Wb + id * 4) = st;
  } else {                                          // cvt fus_w -> Wf (196608 fl)
    int id = (gx - 1856) * 256 + t;
    float4 v = *(const float4*)(fus_w + id * 4);
    ushort4 st; st.x = f2bf(v.x); st.y = f2bf(v.y); st.z = f2bf(v.z); st.w = f2bf(v.w);
    *(ushort4*)(Wf + id * 4) = st;
  }
}

// ---------------- dwconv (dw + pos), all 3 scales in one launch -----------------
__global__ __launch_bounds__(256) void dwconv_all_kernel(const float* __restrict__ x,
    const float* __restrict__ xs2, const float* __restrict__ xs4,
    const float* __restrict__ dw_w, const float* __restrict__ dw_b,
    const float* __restrict__ pos_w, const float* __restrict__ pos_b,
    float* __restrict__ xdwAll, float* __restrict__ posAll) {
  int gx = blockIdx.x;
  const float* src;
  int lgHs, wo, soff;
  if (gx < 4096)      { src = x;   lgHs = 6; wo = 0; soff = 0; }
  else if (gx < 5120) { src = xs2; lgHs = 5; wo = 1; soff = 1048576; gx -= 4096; }
  else                { src = xs4; lgHs = 4; wo = 2; soff = 1310720; gx -= 5120; }
  int Hs = 1 << lgHs;
  int Ns = Hs * Hs;
  int id = gx * 256 + threadIdx.x;                  // c * Ns + n  (within scale)
  int c = id >> (2 * lgHs);
  int n = id & (Ns - 1);
  int y = n >> lgHs, xx0 = n & (Hs - 1);
  const float* w1 = dw_w + wo * 2304 + c * 9;
  const float* w2 = pos_w + wo * 2304 + c * 9;
  const float* sb = src + c * Ns;
  float s1 = dw_b[wo * 256 + c], s2 = pos_b[wo * 256 + c];
  #pragma unroll
  for (int ky = 0; ky < 3; ++ky) {
    int yy = y + ky - 1;
    bool yok = (yy >= 0) && (yy < Hs);
    #pragma unroll
    for (int kx = 0; kx < 3; ++kx) {
      int xc = xx0 + kx - 1;
      bool ok = yok && (xc >= 0) && (xc < Hs);
      float v = ok ? sb[yy * Hs + xc] : 0.f;
      s1 += v * w1[ky * 3 + kx];
      s2 += v * w2[ky * 3 + kx];
    }
  }
  xdwAll[soff + id] = s1;
  posAll[soff + id] = s2;
}

// ---------------- transpose + cvt for all scales / both sources ----------------
// fp32 [256][Ns] -> bf16 [Ns][256]
__global__ __launch_bounds__(256) void transpose_all_kernel(const float* __restrict__ xdwAll,
    const float* __restrict__ posAll, unsigned short* __restrict__ xdwT,
    unsigned short* __restrict__ posT) {
  __shared__ unsigned short lds[64][72];
  int b = blockIdx.x;
  int N, soff, nx;
  if (b < 512)      { N = 4096; soff = 0;       nx = 64; }
  else if (b < 640) { N = 1024; soff = 1048576; nx = 16; b -= 512; }
  else              { N = 256;  soff = 1310720; nx = 4;  b -= 640; }
  const int z = b / (nx * 4);
  const int rem = b % (nx * 4);
  const int c0 = (rem / nx) * 64;
  const int n0 = (rem % nx) * 64;
  const float* src = (z ? posAll : xdwAll) + soff;
  unsigned short* dst = (z ? posT : xdwT) + soff;
  const int t = threadIdx.x;
  #pragma unroll
  for (int p = 0; p < 4; ++p) {
    int c = p * 16 + (t >> 4);
    int nn = (t & 15) * 4;
    float4 v = *(const float4*)(src + (size_t)(c0 + c) * N + n0 + nn);
    lds[nn + 0][c] = f2bf(v.x);
    lds[nn + 1][c] = f2bf(v.y);
    lds[nn + 2][c] = f2bf(v.z);
    lds[nn + 3][c] = f2bf(v.w);
  }
  __syncthreads();
  int n = t >> 2, seg = (t & 3) * 16;
  *(bf16x8*)(dst + (size_t)(n0 + n) * 256 + c0 + seg)     = *(const bf16x8*)&lds[n][seg];
  *(bf16x8*)(dst + (size_t)(n0 + n) * 256 + c0 + seg + 8) = *(const bf16x8*)&lds[n][seg + 8];
}

// ---------------- QKV GEMM via bf16 MFMA, all scales in one launch --------------
__global__ __launch_bounds__(256) void gemm_qkv_all(const unsigned short* __restrict__ WbA,
    const unsigned short* __restrict__ xdwTA, const float* __restrict__ biasA,
    const unsigned short* __restrict__ posTA, unsigned short* __restrict__ qkvTA,
    unsigned short* __restrict__ VbA) {
  int by = blockIdx.y;
  int Ns, tro;                                      // tro = element offset into xdwT/posT
  const unsigned short *Wb, *xdwT, *posT;
  unsigned short *qkvT, *Vb;
  const float* bias;
  if (by < 64) {
    Ns = 4096; tro = 0;
    Wb = WbA; bias = biasA; qkvT = qkvTA; Vb = VbA;
  } else if (by < 80) {
    Ns = 1024; tro = 1048576; by -= 64;
    Wb = WbA + 196608; bias = biasA + 768;
    qkvT = qkvTA + 2097152; Vb = VbA + 1048576;
  } else {
    Ns = 256; tro = 1310720; by -= 80;
    Wb = WbA + 393216; bias = biasA + 1536;
    qkvT = qkvTA + 2621440; Vb = VbA + 1310720;
  }
  xdwT = xdwTA + tro; posT = posTA + tro;
  const int t = threadIdx.x;
  const int wave = t >> 6, lane = t & 63;
  const int ln = lane & 15, quad = lane >> 4;
  const int o0 = blockIdx.x * 64 + (wave & 1) * 32;
  const int n0 = by * 64 + (wave >> 1) * 32;
  const unsigned short* a0 = Wb + (size_t)(o0 + ln) * 256 + quad * 8;
  const unsigned short* a1 = a0 + 16 * 256;
  const unsigned short* b0 = xdwT + (size_t)(n0 + ln) * 256 + quad * 8;
  const unsigned short* b1 = b0 + 16 * 256;
  f32x4 acc[2][2] = {};
  #pragma unroll
  for (int ks = 0; ks < 8; ++ks) {
    bf16x8 af0 = *(const bf16x8*)(a0 + ks * 32);
    bf16x8 af1 = *(const bf16x8*)(a1 + ks * 32);
    bf16x8 bv0 = *(const bf16x8*)(b0 + ks * 32);
    bf16x8 bv1 = *(const bf16x8*)(b1 + ks * 32);
    acc[0][0] = __builtin_amdgcn_mfma_f32_16x16x32_bf16(af0, bv0, acc[0][0], 0, 0, 0);
    acc[0][1] = __builtin_amdgcn_mfma_f32_16x16x32_bf16(af0, bv1, acc[0][1], 0, 0, 0);
    acc[1][0] = __builtin_amdgcn_mfma_f32_16x16x32_bf16(af1, bv0, acc[1][0], 0, 0, 0);
    acc[1][1] = __builtin_amdgcn_mfma_f32_16x16x32_bf16(af1, bv1, acc[1][1], 0, 0, 0);
  }
  const int cat = blockIdx.x >> 2;                  // 0=q 1=k 2=v
  #pragma unroll
  for (int mt = 0; mt < 2; ++mt) {
    int ot = o0 + mt * 16 + quad * 4;
    float bs0 = bias[ot], bs1 = bias[ot + 1], bs2 = bias[ot + 2], bs3 = bias[ot + 3];
    #pragma unroll
    for (int nt = 0; nt < 2; ++nt) {
      int nn = n0 + nt * 16 + ln;
      f32x4 v = acc[mt][nt];
      v.x += bs0; v.y += bs1; v.z += bs2; v.w += bs3;
      if (cat < 2) {
        ushort4 p4 = *(const ushort4*)(posT + (size_t)nn * 256 + (ot & 255));
        v.x += bf2f(p4.x); v.y += bf2f(p4.y); v.z += bf2f(p4.z); v.w += bf2f(p4.w);
        if (cat == 0) { v.x *= QSCALE; v.y *= QSCALE; v.z *= QSCALE; v.w *= QSCALE; }
        ushort4 st;
        st.x = f2bf(v.x); st.y = f2bf(v.y); st.z = f2bf(v.z); st.w = f2bf(v.w);
        *(ushort4*)(qkvT + (size_t)nn * 512 + ot) = st;
      } else {
        Vb[(size_t)(ot - 512 + 0) * Ns + nn] = f2bf(v.x);
        Vb[(size_t)(ot - 512 + 1) * Ns + nn] = f2bf(v.y);
        Vb[(size_t)(ot - 512 + 2) * Ns + nn] = f2bf(v.z);
        Vb[(size_t)(ot - 512 + 3) * Ns + nn] = f2bf(v.w);
      }
    }
  }
}

// ---------------- attention: barrier-free, direct global fragments (round-4 body)
// partials stored bf16.  grid (qtiles, heads, splits); block 256 = 4 waves x 32 q.
__global__ __launch_bounds__(256) void attn2_kernel(const unsigned short* __restrict__ qkvT,
    const unsigned short* __restrict__ Vb, unsigned short* __restrict__ accp,
    float* __restrict__ lsump, int Ns, int lgMs) {
  __shared__ unsigned short pt_lds[4 * 32 * 72];    // wave-private P^T [n][m], pad 72
  const int t = threadIdx.x;
  const int wave = t >> 6, lane = t & 63;
  const int ln = lane & 15, quad = lane >> 4;
  const int h = blockIdx.y, sp = blockIdx.z;
  const int n0 = blockIdx.x * 128 + wave * 32;
  const unsigned short* qb = qkvT + (size_t)n0 * 512 + h * 32 + quad * 8;
  bf16x8 qf0 = *(const bf16x8*)(qb + (size_t)ln * 512);
  bf16x8 qf1 = *(const bf16x8*)(qb + (size_t)(16 + ln) * 512);
  unsigned short* ptw = pt_lds + wave * (32 * 72);
  f32x4 acc[2][2] = {};
  float lsum0 = 0.f, lsum1 = 0.f;
  const f32x4 zero = {0.f, 0.f, 0.f, 0.f};
  const int m0s = sp << lgMs;
  const int nch = 1 << (lgMs - 6);
  const unsigned short* kb = qkvT + (size_t)(m0s + ln) * 512 + 256 + h * 32 + quad * 8;
  const unsigned short* vb = Vb + (size_t)(h * 32 + ln) * Ns + m0s + quad * 8;
  for (int ch = 0; ch < nch; ++ch) {
    const unsigned short* kc = kb + (size_t)ch * 64 * 512;
    const unsigned short* vc = vb + ch * 64;
    bf16x8 kf0 = *(const bf16x8*)(kc);
    bf16x8 kf1 = *(const bf16x8*)(kc + 16 * 512);
    bf16x8 kf2 = *(const bf16x8*)(kc + 32 * 512);
    bf16x8 kf3 = *(const bf16x8*)(kc + 48 * 512);
    bf16x8 vf00 = *(const bf16x8*)(vc);
    bf16x8 vf01 = *(const bf16x8*)(vc + 32);
    bf16x8 vf10 = *(const bf16x8*)(vc + (size_t)16 * Ns);
    bf16x8 vf11 = *(const bf16x8*)(vc + (size_t)16 * Ns + 32);
    f32x4 s[4][2];
    s[0][0] = __builtin_amdgcn_mfma_f32_16x16x32_bf16(kf0, qf0, zero, 0, 0, 0);
    s[0][1] = __builtin_amdgcn_mfma_f32_16x16x32_bf16(kf0, qf1, zero, 0, 0, 0);
    s[1][0] = __builtin_amdgcn_mfma_f32_16x16x32_bf16(kf1, qf0, zero, 0, 0, 0);
    s[1][1] = __builtin_amdgcn_mfma_f32_16x16x32_bf16(kf1, qf1, zero, 0, 0, 0);
    s[2][0] = __builtin_amdgcn_mfma_f32_16x16x32_bf16(kf2, qf0, zero, 0, 0, 0);
    s[2][1] = __builtin_amdgcn_mfma_f32_16x16x32_bf16(kf2, qf1, zero, 0, 0, 0);
    s[3][0] = __builtin_amdgcn_mfma_f32_16x16x32_bf16(kf3, qf0, zero, 0, 0, 0);
    s[3][1] = __builtin_amdgcn_mfma_f32_16x16x32_bf16(kf3, qf1, zero, 0, 0, 0);
    #pragma unroll
    for (int mt = 0; mt < 4; ++mt) {
      #pragma unroll
      for (int nt = 0; nt < 2; ++nt) {
        float e0 = EXP2(s[mt][nt].x);
        float e1 = EXP2(s[mt][nt].y);
        float e2 = EXP2(s[mt][nt].z);
        float e3 = EXP2(s[mt][nt].w);
        if (nt == 0) lsum0 += (e0 + e1) + (e2 + e3);
        else         lsum1 += (e0 + e1) + (e2 + e3);
        uint2 pk;                                   // bf16-truncate pack, 1 op/pair
        pk.x = __builtin_amdgcn_perm(__float_as_uint(e1), __float_as_uint(e0), 0x07060302);
        pk.y = __builtin_amdgcn_perm(__float_as_uint(e3), __float_as_uint(e2), 0x07060302);
        *(uint2*)&ptw[(nt * 16 + ln) * 72 + mt * 16 + quad * 4] = pk;
      }
    }
    #pragma unroll
    for (int ks = 0; ks < 2; ++ks) {
      bf16x8 pf0 = *(const bf16x8*)&ptw[ln * 72 + ks * 32 + quad * 8];
      bf16x8 pf1 = *(const bf16x8*)&ptw[(16 + ln) * 72 + ks * 32 + quad * 8];
      bf16x8 va = ks ? vf01 : vf00;
      bf16x8 vbf = ks ? vf11 : vf10;
      acc[0][0] = __builtin_amdgcn_mfma_f32_16x16x32_bf16(va, pf0, acc[0][0], 0, 0, 0);
      acc[0][1] = __builtin_amdgcn_mfma_f32_16x16x32_bf16(va, pf1, acc[0][1], 0, 0, 0);
      acc[1][0] = __builtin_amdgcn_mfma_f32_16x16x32_bf16(vbf, pf0, acc[1][0], 0, 0, 0);
      acc[1][1] = __builtin_amdgcn_mfma_f32_16x16x32_bf16(vbf, pf1, acc[1][1], 0, 0, 0);
    }
  }
  lsum0 += __shfl_xor(lsum0, 16, 64);
  lsum0 += __shfl_xor(lsum0, 32, 64);
  lsum1 += __shfl_xor(lsum1, 16, 64);
  lsum1 += __shfl_xor(lsum1, 32, 64);
  unsigned short* ap = accp + ((size_t)sp * 256 + h * 32) * Ns;
  #pragma unroll
  for (int dt = 0; dt < 2; ++dt) {
    #pragma unroll
    for (int r = 0; r < 4; ++r) {
      int cl = dt * 16 + quad * 4 + r;
      ap[(size_t)cl * Ns + n0 + ln]      = f2bf(((const float*)&acc[dt][0])[r]);
      ap[(size_t)cl * Ns + n0 + 16 + ln] = f2bf(((const float*)&acc[dt][1])[r]);
    }
  }
  if (lane < 16) {
    float* lp = lsump + ((size_t)sp * 8 + h) * Ns + n0;
    lp[lane]      = lsum0;
    lp[16 + lane] = lsum1;
  }
}

// ---------------- combine s2 (8 splits) + s4 (4 splits) in one launch -----------
__global__ __launch_bounds__(256) void combine24_kernel(const unsigned short* __restrict__ p2,
    const float* __restrict__ ls2, const unsigned short* __restrict__ p4,
    const float* __restrict__ ls4, float* __restrict__ out2, float* __restrict__ out4) {
  int id = blockIdx.x * 256 + threadIdx.x;
  if (id < 262144) {                                // s2: 256 x 1024
    int n = id & 1023, h = id >> 15;
    float v = 0.f, d = 0.f;
    #pragma unroll
    for (int sp = 0; sp < 8; ++sp) {
      v += bf2f(p2[sp * 262144 + id]);
      d += ls2[sp * 8192 + h * 1024 + n];
    }
    out2[id] = v / d;
  } else {                                          // s4: 256 x 256
    int idl = id - 262144;
    int n = idl & 255, h = idl >> 13;
    float v = 0.f, d = 0.f;
    #pragma unroll
    for (int sp = 0; sp < 4; ++sp) {
      v += bf2f(p4[sp * 65536 + idl]);
      d += ls4[sp * 2048 + h * 256 + n];
    }
    out4[idl] = v / d;
  }
}

// ---------------- build catT bf16 [4096][768] directly --------------------------
// by 0..3:  c 0..255   = attn-s1 combine (8 bf16 partial splits / lsum1)
// by 4..7:  c 256..511 = bilinear upsample of out2 (32x32)
// by 8..11: c 512..767 = bilinear upsample of out4 (16x16)
__global__ __launch_bounds__(256) void build_catT_kernel(const unsigned short* __restrict__ accp,
    const float* __restrict__ lsum1, const float* __restrict__ out2,
    const float* __restrict__ out4, unsigned short* __restrict__ catT) {
  __shared__ unsigned short lds[64][72];
  const int t = threadIdx.x;
  const int n0 = blockIdx.x * 64;
  const int by = blockIdx.y;
  const int c0 = by * 64;
  if (by < 4) {
    #pragma unroll
    for (int p = 0; p < 4; ++p) {
      int ct = p * 16 + (t >> 4);
      int c = c0 + ct;
      int h = c >> 5;
      int nn = (t & 15) * 4;
      float vs[4] = {0.f, 0.f, 0.f, 0.f};
      float ds[4] = {0.f, 0.f, 0.f, 0.f};
      #pragma unroll
      for (int sp = 0; sp < 8; ++sp) {
        ushort4 a = *(const ushort4*)(accp + (size_t)sp * 1048576 + (size_t)c * 4096 + n0 + nn);
        vs[0] += bf2f(a.x); vs[1] += bf2f(a.y); vs[2] += bf2f(a.z); vs[3] += bf2f(a.w);
        float4 dd = *(const float4*)(lsum1 + (size_t)sp * 32768 + (size_t)h * 4096 + n0 + nn);
        ds[0] += dd.x; ds[1] += dd.y; ds[2] += dd.z; ds[3] += dd.w;
      }
      lds[nn + 0][ct] = f2bf(vs[0] / ds[0]);
      lds[nn + 1][ct] = f2bf(vs[1] / ds[1]);
      lds[nn + 2][ct] = f2bf(vs[2] / ds[2]);
      lds[nn + 3][ct] = f2bf(vs[3] / ds[3]);
    }
  } else {
    const bool s2 = by < 8;
    const float* src = s2 ? out2 : out4;
    const int Hs = s2 ? 32 : 16;
    const int coff = s2 ? 256 : 512;
    const float sc = (float)Hs / 64.0f;
    #pragma unroll
    for (int p = 0; p < 4; ++p) {
      int ct = p * 16 + (t >> 4);
      const float* s = src + (size_t)(c0 - coff + ct) * Hs * Hs;
      int nn = (t & 15) * 4;
      #pragma unroll
      for (int i = 0; i < 4; ++i) {
        int n = n0 + nn + i;
        int y = n >> 6, x = n & 63;
        float fy = ((float)y + 0.5f) * sc - 0.5f;
        float fx = ((float)x + 0.5f) * sc - 0.5f;
        float fy0 = floorf(fy), fx0 = floorf(fx);
        int y0 = (int)fy0, x0 = (int)fx0;
        float ty = fy - fy0, tx = fx - fx0;
        int y0c = min(max(y0, 0), Hs - 1), y1c = min(max(y0 + 1, 0), Hs - 1);
        int x0c = min(max(x0, 0), Hs - 1), x1c = min(max(x0 + 1, 0), Hs - 1);
        float v00 = s[y0c * Hs + x0c], v01 = s[y0c * Hs + x1c];
        float v10 = s[y1c * Hs + x0c], v11 = s[y1c * Hs + x1c];
        float v0 = v00 + (v01 - v00) * tx;
        float v1 = v10 + (v11 - v10) * tx;
        lds[nn + i][ct] = f2bf(v0 + (v1 - v0) * ty);
      }
    }
  }
  __syncthreads();
  int n = t >> 2, seg = (t & 3) * 16;
  *(bf16x8*)(catT + (size_t)(n0 + n) * 768 + c0 + seg)     = *(const bf16x8*)&lds[n][seg];
  *(bf16x8*)(catT + (size_t)(n0 + n) * 768 + c0 + seg + 8) = *(const bf16x8*)&lds[n][seg + 8];
}

// ---------------- fusion GEMM via bf16 MFMA, split-K=3 --------------------------
__global__ __launch_bounds__(256) void gemm_fus_mfma(const unsigned short* __restrict__ Wf,
    const unsigned short* __restrict__ catT, float* __restrict__ part) {
  const int t = threadIdx.x;
  const int wave = t >> 6, lane = t & 63;
  const int ln = lane & 15, quad = lane >> 4;
  const int o0 = blockIdx.x * 64 + (wave & 1) * 32;
  const int n0 = blockIdx.y * 64 + (wave >> 1) * 32;
  const int sp = blockIdx.z;
  const int k0 = sp * 256;
  const unsigned short* a0 = Wf + (size_t)(o0 + ln) * 768 + k0 + quad * 8;
  const unsigned short* a1 = a0 + 16 * 768;
  const unsigned short* b0 = catT + (size_t)(n0 + ln) * 768 + k0 + quad * 8;
  const unsigned short* b1 = b0 + 16 * 768;
  f32x4 acc[2][2] = {};
  #pragma unroll
  for (int ks = 0; ks < 8; ++ks) {
    bf16x8 af0 = *(const bf16x8*)(a0 + ks * 32);
    bf16x8 af1 = *(const bf16x8*)(a1 + ks * 32);
    bf16x8 bv0 = *(const bf16x8*)(b0 + ks * 32);
    bf16x8 bv1 = *(const bf16x8*)(b1 + ks * 32);
    acc[0][0] = __builtin_amdgcn_mfma_f32_16x16x32_bf16(af0, bv0, acc[0][0], 0, 0, 0);
    acc[0][1] = __builtin_amdgcn_mfma_f32_16x16x32_bf16(af0, bv1, acc[0][1], 0, 0, 0);
    acc[1][0] = __builtin_amdgcn_mfma_f32_16x16x32_bf16(af1, bv0, acc[1][0], 0, 0, 0);
    acc[1][1] = __builtin_amdgcn_mfma_f32_16x16x32_bf16(af1, bv1, acc[1][1], 0, 0, 0);
  }
  float* pp = part + (size_t)sp * 1048576;
  #pragma unroll
  for (int mt = 0; mt < 2; ++mt) {
    #pragma unroll
    for (int nt = 0; nt < 2; ++nt) {
      #pragma unroll
      for (int r = 0; r < 4; ++r) {
        pp[(size_t)(o0 + mt * 16 + quad * 4 + r) * 4096 + n0 + nt * 16 + ln] =
            ((const float*)&acc[mt][nt])[r];
      }
    }
  }
}

// ---------------- fusion combine: out = p0+p1+p2 + bias -------------------------
__global__ __launch_bounds__(256) void fus_combine_kernel(const float* __restrict__ part,
    const float* __restrict__ bias, float* __restrict__ out) {
  int id = blockIdx.x * 256 + threadIdx.x;          // float4 index
  int o = id >> 10;
  float4 v0 = *(const float4*)(part + id * 4);
  float4 v1 = *(const float4*)(part + 1048576 + id * 4);
  float4 v2 = *(const float4*)(part + 2097152 + id * 4);
  float bs = bias[o];
  float4 r;
  r.x = v0.x + v1.x + v2.x + bs;
  r.y = v0.y + v1.y + v2.y + bs;
  r.z = v0.z + v1.z + v2.z + bs;
  r.w = v0.w + v1.w + v2.w + bs;
  *(float4*)(out + id * 4) = r;
}

extern "C" void kernel_launch(void* const* d_in, const int* in_sizes, int n_in,
                              void* d_out, int out_size, void* d_ws, size_t ws_size,
                              hipStream_t stream) {
  const float* x     = (const float*)d_in[0];
  const float* dw_w  = (const float*)d_in[1];
  const float* dw_b  = (const float*)d_in[2];
  const float* pw_w  = (const float*)d_in[3];
  const float* pw_b  = (const float*)d_in[4];
  const float* pos_w = (const float*)d_in[5];
  const float* pos_b = (const float*)d_in[6];
  const float* fus_w = (const float*)d_in[7];
  const float* fus_b = (const float*)d_in[8];
  float* out = (float*)d_out;
  float* ws = (float*)d_ws;

  // ws layout (floats), total 12,058,624 fl = 46.0 MB (aliasing noted inline)
  float* xdwAll = ws;                        // 1,376,256  [attn s2/s4 bf16 partials later]
  float* posAll = ws + 1376256;              // 1,376,256  [lsum1/2/4 + out2/out4 later]
  float* accpF  = ws + 2752512;              // 4,194,304  [xs2/xs4 early; s1 bf16 partials; fusion part]
  unsigned short* xdwT = (unsigned short*)(ws + 6946816);   // 1,376,256 us
  unsigned short* posT = (unsigned short*)(ws + 7634944);   // 1,376,256 us
  unsigned short* qkvT = (unsigned short*)(ws + 8323072);   // 2,752,512 us
  unsigned short* Vb   = (unsigned short*)(ws + 9699328);   // 1,376,256 us
  unsigned short* catT = (unsigned short*)(ws + 10387456);  // 3,145,728 us [Wb early]
  unsigned short* Wf   = (unsigned short*)(ws + 11960320);  //   196,608 us

  float* xs2 = accpF;                        // dead before attn-s1 writes accp
  float* xs4 = accpF + 262144;
  unsigned short* Wb = catT;                 // dead before build_catT writes catT
  unsigned short* accp = (unsigned short*)accpF;            // 8,388,608 us (8 splits)
  float* lsump1 = posAll;                    // 262,144 (8sp x 8h x 4096)
  float* lsump2 = posAll + 262144;           // 65,536
  float* lsump4 = posAll + 327680;           // 8,192
  float* out2   = posAll + 335872;           // 262,144
  float* out4   = posAll + 598016;           // 65,536
  unsigned short* p2 = (unsigned short*)xdwAll;             // 2,097,152 us (8 splits)
  unsigned short* p4 = (unsigned short*)xdwAll + 2097152;   //   262,144 us (4 splits)
  float* part = accpF;                       // fusion partials (accp dead then)

  prep_kernel<<<2048, 256, 0, stream>>>(x, pw_w, fus_w, xs2, xs4, Wb, Wf);
  dwconv_all_kernel<<<5376, 256, 0, stream>>>(x, xs2, xs4, dw_w, dw_b, pos_w, pos_b,
                                              xdwAll, posAll);
  transpose_all_kernel<<<672, 256, 0, stream>>>(xdwAll, posAll, xdwT, posT);
  gemm_qkv_all<<<dim3(12, 84), 256, 0, stream>>>(Wb, xdwT, pw_b, posT, qkvT, Vb);

  attn2_kernel<<<dim3(32, 8, 8), 256, 0, stream>>>(qkvT, Vb, accp, lsump1, 4096, 9);
  attn2_kernel<<<dim3(8, 8, 8), 256, 0, stream>>>(qkvT + 2097152, Vb + 1048576,
                                                  p2, lsump2, 1024, 7);
  attn2_kernel<<<dim3(2, 8, 4), 256, 0, stream>>>(qkvT + 2621440, Vb + 1310720,
                                                  p4, lsump4, 256, 6);
  combine24_kernel<<<1280, 256, 0, stream>>>(p2, lsump2, p4, lsump4, out2, out4);

  build_catT_kernel<<<dim3(64, 12), 256, 0, stream>>>(accp, lsump1, out2, out4, catT);
  gemm_fus_mfma<<<dim3(4, 64, 3), 256, 0, stream>>>(Wf, catT, part);
  fus_combine_kernel<<<1024, 256, 0, stream>>>(part, fus_b, out);
}